// Round 1
// baseline (2161.096 us; speedup 1.0000x reference)
//
#include <hip/hip_runtime.h>
#include <math.h>

#define NN 50000
#define NE 800000
#define HD 64

__device__ __forceinline__ float wave_sum(float v) {
  #pragma unroll
  for (int off = 32; off > 0; off >>= 1) v += __shfl_xor(v, off, 64);
  return v;
}

// ---------------- edge prep: edge_type + degree counts + layer0 aggregation ----------------
__global__ __launch_bounds__(256) void edge_prep(
    const int* __restrict__ ei, const float* __restrict__ ea, const float* __restrict__ x,
    int* __restrict__ et, int* __restrict__ cnt, float* __restrict__ agg0)
{
  int e = blockIdx.x * blockDim.x + threadIdx.x;
  if (e >= NE) return;
  float dist = ea[e * 6];
  const float q1 = log1pf(5000.0f);
  const float q2 = log1pf(10000.0f);
  int r = (dist > q1 ? 1 : 0) + (dist > q2 ? 1 : 0);
  et[e] = r;
  int s = ei[e], d = ei[NE + e];
  atomicAdd(&cnt[d * 3 + r], 1);
  #pragma unroll
  for (int k = 0; k < 3; k++)
    atomicAdd(&agg0[d * 9 + r * 3 + k], x[s * 3 + k]);
}

__global__ __launch_bounds__(256) void make_dinv(const int* __restrict__ cnt, float* __restrict__ dinv) {
  int i = blockIdx.x * blockDim.x + threadIdx.x;
  if (i < NN * 3) {
    int c = cnt[i];
    dinv[i] = 1.0f / (float)(c > 1 ? c : 1);
  }
}

// ---------------- layer 0 node update (IN=3) + relu + residual + LN ----------------
__global__ __launch_bounds__(256) void node0_kernel(
    const float* __restrict__ x, const float* __restrict__ agg0, const float* __restrict__ dinv,
    const float* __restrict__ w0, const float* __restrict__ root0, const float* __restrict__ b0,
    const float* __restrict__ res_w, const float* __restrict__ res_b,
    const float* __restrict__ g, const float* __restrict__ bb, float* __restrict__ h1)
{
  int wid = __builtin_amdgcn_readfirstlane((int)((blockIdx.x * blockDim.x + threadIdx.x) >> 6));
  int lane = threadIdx.x & 63;
  int n0 = wid * 8;
  if (n0 >= NN) return;
  float wr[3], ww[9], wres[3];
  #pragma unroll
  for (int i = 0; i < 3; i++) { wr[i] = root0[i * HD + lane]; wres[i] = res_w[i * HD + lane]; }
  #pragma unroll
  for (int i = 0; i < 9; i++) ww[i] = w0[i * HD + lane];
  float vb = b0[lane], vrb = res_b[lane], vg = g[lane], vbb = bb[lane];
  #pragma unroll
  for (int k = 0; k < 8; k++) {
    int nk = n0 + k;
    float xv[3];
    #pragma unroll
    for (int i = 0; i < 3; i++) xv[i] = x[nk * 3 + i];
    float v = vb;
    #pragma unroll
    for (int i = 0; i < 3; i++) v = fmaf(xv[i], wr[i], v);
    #pragma unroll
    for (int r = 0; r < 3; r++) {
      float s = 0.f;
      #pragma unroll
      for (int i = 0; i < 3; i++) s = fmaf(agg0[nk * 9 + r * 3 + i], ww[r * 3 + i], s);
      v = fmaf(dinv[nk * 3 + r], s, v);
    }
    v = fmaxf(v, 0.f);
    float res = vrb;
    #pragma unroll
    for (int i = 0; i < 3; i++) res = fmaf(xv[i], wres[i], res);
    float t = v + res;
    float mu = wave_sum(t) * 0.015625f;
    float dt = t - mu;
    float var = wave_sum(dt * dt) * 0.015625f;
    h1[nk * HD + lane] = dt * rsqrtf(var + 1e-5f) * vg + vbb;
  }
}

// ---------------- edge aggregation for H=64 layers ----------------
__global__ __launch_bounds__(256) void agg_h(
    const float* __restrict__ hin, const int* __restrict__ ei, const int* __restrict__ et,
    float* __restrict__ agg)
{
  int t = blockIdx.x * blockDim.x + threadIdx.x;
  if (t >= NE * 16) return;
  int e = t >> 4, c = t & 15;
  int s = ei[e], d = ei[NE + e], r = et[e];
  const float4 v = *(const float4*)(hin + s * HD + c * 4);
  float* p = agg + d * 192 + r * HD + c * 4;
  atomicAdd(p + 0, v.x);
  atomicAdd(p + 1, v.y);
  atomicAdd(p + 2, v.z);
  atomicAdd(p + 3, v.w);
}

// ---------------- H->H node update + relu + residual + LN ----------------
__global__ __launch_bounds__(256) void node_hh(
    const float* __restrict__ hin, const float* __restrict__ agg, const float* __restrict__ dinv,
    const float* __restrict__ W, const float* __restrict__ root, const float* __restrict__ bias,
    const float* __restrict__ g, const float* __restrict__ bb, float* __restrict__ hout)
{
  int wid = __builtin_amdgcn_readfirstlane((int)((blockIdx.x * blockDim.x + threadIdx.x) >> 6));
  int lane = threadIdx.x & 63;
  int n0 = wid * 8;
  if (n0 >= NN) return;
  float accR[8], accA0[8], accA1[8], accA2[8];
  #pragma unroll
  for (int k = 0; k < 8; k++) { accR[k] = 0.f; accA0[k] = 0.f; accA1[k] = 0.f; accA2[k] = 0.f; }
  #pragma unroll 4
  for (int i = 0; i < HD; i++) {
    float wr  = root[i * HD + lane];
    float wa0 = W[i * HD + lane];
    float wa1 = W[4096 + i * HD + lane];
    float wa2 = W[8192 + i * HD + lane];
    #pragma unroll
    for (int k = 0; k < 8; k++) {
      int nk = n0 + k;
      accR[k]  = fmaf(hin[nk * HD + i],        wr,  accR[k]);
      accA0[k] = fmaf(agg[nk * 192 + i],       wa0, accA0[k]);
      accA1[k] = fmaf(agg[nk * 192 + 64 + i],  wa1, accA1[k]);
      accA2[k] = fmaf(agg[nk * 192 + 128 + i], wa2, accA2[k]);
    }
  }
  float vb = bias[lane], vg = g[lane], vbb = bb[lane];
  #pragma unroll
  for (int k = 0; k < 8; k++) {
    int nk = n0 + k;
    float v = vb + accR[k];
    v = fmaf(dinv[nk * 3 + 0], accA0[k], v);
    v = fmaf(dinv[nk * 3 + 1], accA1[k], v);
    v = fmaf(dinv[nk * 3 + 2], accA2[k], v);
    v = fmaxf(v, 0.f);
    float t = v + hin[nk * HD + lane];
    float mu = wave_sum(t) * 0.015625f;
    float dt = t - mu;
    float var = wave_sum(dt * dt) * 0.015625f;
    hout[nk * HD + lane] = dt * rsqrtf(var + 1e-5f) * vg + vbb;
  }
}

// ---------------- per-edge decoder MLP ----------------
__global__ __launch_bounds__(256) void decoder_kernel(
    const float* __restrict__ h3, const int* __restrict__ ei, const float* __restrict__ ea,
    const float* __restrict__ W1, const float* __restrict__ B1,
    const float* __restrict__ W2, const float* __restrict__ B2,
    const float* __restrict__ W3, const float* __restrict__ B3,
    float* __restrict__ out)
{
  int e = blockIdx.x * blockDim.x + threadIdx.x;
  if (e >= NE) return;
  int s = ei[e], d = ei[NE + e];
  const float4* hs4 = (const float4*)(h3 + s * HD);
  const float4* hd4 = (const float4*)(h3 + d * HD);
  float z[32];
  #pragma unroll
  for (int o = 0; o < 32; o++) z[o] = B1[o];
  for (int j4 = 0; j4 < 16; j4++) {
    float4 a = hs4[j4], b = hd4[j4];
    float fa[4] = {a.x, a.y, a.z, a.w};
    float fb[4] = {b.x, b.y, b.z, b.w};
    #pragma unroll
    for (int jj = 0; jj < 4; jj++) {
      int j = j4 * 4 + jj;
      float va = fa[jj], vbv = fb[jj];
      float vab = fabsf(va - vbv), vm = va * vbv;
      const float* w1a = W1 + j * 32;
      const float* w1b = W1 + (64 + j) * 32;
      const float* w1c = W1 + (128 + j) * 32;
      const float* w1d = W1 + (192 + j) * 32;
      #pragma unroll
      for (int o = 0; o < 32; o++) {
        float acc = z[o];
        acc = fmaf(va, w1a[o], acc);
        acc = fmaf(vbv, w1b[o], acc);
        acc = fmaf(vab, w1c[o], acc);
        acc = fmaf(vm, w1d[o], acc);
        z[o] = acc;
      }
    }
  }
  #pragma unroll
  for (int k = 0; k < 6; k++) {
    float v = ea[e * 6 + k];
    const float* wk = W1 + (256 + k) * 32;
    #pragma unroll
    for (int o = 0; o < 32; o++) z[o] = fmaf(v, wk[o], z[o]);
  }
  float z2[16];
  #pragma unroll
  for (int p = 0; p < 16; p++) z2[p] = B2[p];
  #pragma unroll
  for (int o = 0; o < 32; o++) {
    float v = fmaxf(z[o], 0.f);
    #pragma unroll
    for (int p = 0; p < 16; p++) z2[p] = fmaf(v, W2[o * 16 + p], z2[p]);
  }
  float r = B3[0];
  #pragma unroll
  for (int p = 0; p < 16; p++) r = fmaf(fmaxf(z2[p], 0.f), W3[p], r);
  out[e] = r;
}

extern "C" void kernel_launch(void* const* d_in, const int* in_sizes, int n_in,
                              void* d_out, int out_size, void* d_ws, size_t ws_size,
                              hipStream_t stream) {
  const float* x      = (const float*)d_in[0];
  const int*   ei     = (const int*)d_in[1];
  const float* ea     = (const float*)d_in[2];
  const float* w0     = (const float*)d_in[3];
  const float* root0  = (const float*)d_in[4];
  const float* b0     = (const float*)d_in[5];
  const float* w1     = (const float*)d_in[6];
  const float* root1  = (const float*)d_in[7];
  const float* b1     = (const float*)d_in[8];
  const float* w2     = (const float*)d_in[9];
  const float* root2  = (const float*)d_in[10];
  const float* b2     = (const float*)d_in[11];
  const float* ln_g0  = (const float*)d_in[12];
  const float* ln_b0  = (const float*)d_in[13];
  const float* ln_g1  = (const float*)d_in[14];
  const float* ln_b1  = (const float*)d_in[15];
  const float* ln_g2  = (const float*)d_in[16];
  const float* ln_b2  = (const float*)d_in[17];
  const float* res_w  = (const float*)d_in[18];
  const float* res_b  = (const float*)d_in[19];
  const float* dec_w1 = (const float*)d_in[20];
  const float* dec_b1 = (const float*)d_in[21];
  const float* dec_w2 = (const float*)d_in[22];
  const float* dec_b2 = (const float*)d_in[23];
  const float* dec_w3 = (const float*)d_in[24];
  const float* dec_b3 = (const float*)d_in[25];

  char* ws = (char*)d_ws;
  int*   et   = (int*)(ws + 0);               // E ints            = 3,200,000 B
  int*   cnt  = (int*)(ws + 3200000);         // N*3 ints          =   600,000 B
  float* agg0 = (float*)(ws + 3800000);       // N*9 floats        = 1,800,000 B
  float* agg  = (float*)(ws + 5600000);       // N*192 floats      = 38,400,000 B
  float* dinv = (float*)(ws + 44000000);      // N*3 floats        =   600,000 B
  float* h1   = (float*)(ws + 44600000);      // N*64 floats       = 12,800,000 B
  float* h2   = (float*)(ws + 57400000);
  float* h3   = (float*)(ws + 70200000);      // end 83,000,000 B

  // zero cnt + agg0 + agg in one shot (contiguous)
  hipMemsetAsync(cnt, 0, 600000 + 1800000 + 38400000, stream);

  edge_prep<<<(NE + 255) / 256, 256, 0, stream>>>(ei, ea, x, et, cnt, agg0);
  make_dinv<<<(NN * 3 + 255) / 256, 256, 0, stream>>>(cnt, dinv);

  const int node_blocks = (NN / 8 + 3) / 4;  // 6250 waves, 4 waves/block
  node0_kernel<<<node_blocks, 256, 0, stream>>>(x, agg0, dinv, w0, root0, b0,
                                                res_w, res_b, ln_g0, ln_b0, h1);

  agg_h<<<(NE * 16) / 256, 256, 0, stream>>>(h1, ei, et, agg);
  node_hh<<<node_blocks, 256, 0, stream>>>(h1, agg, dinv, w1, root1, b1, ln_g1, ln_b1, h2);

  hipMemsetAsync(agg, 0, 38400000, stream);
  agg_h<<<(NE * 16) / 256, 256, 0, stream>>>(h2, ei, et, agg);
  node_hh<<<node_blocks, 256, 0, stream>>>(h2, agg, dinv, w2, root2, b2, ln_g2, ln_b2, h3);

  decoder_kernel<<<(NE + 255) / 256, 256, 0, stream>>>(h3, ei, ea, dec_w1, dec_b1,
                                                       dec_w2, dec_b2, dec_w3, dec_b3,
                                                       (float*)d_out);
}

// Round 2
// 855.047 us; speedup vs baseline: 2.5275x; 2.5275x over previous
//
#include <hip/hip_runtime.h>
#include <math.h>

#define NN 50000
#define NE 800000
#define HD 64
#define NB 196  // ceil(50000/256)

__device__ __forceinline__ float wave_sum(float v) {
  #pragma unroll
  for (int off = 32; off > 0; off >>= 1) v += __shfl_xor(v, off, 64);
  return v;
}

// ---------------- edge prep: edge_type + per-(dst,rel) histogram + layer0 agg ----------------
__global__ __launch_bounds__(256) void edge_prep(
    const int* __restrict__ ei, const float* __restrict__ ea, const float* __restrict__ x,
    int* __restrict__ et, int* __restrict__ cntR, float* __restrict__ agg0)
{
  int e = blockIdx.x * blockDim.x + threadIdx.x;
  if (e >= NE) return;
  float dist = ea[e * 6];
  const float q1 = log1pf(5000.0f);
  const float q2 = log1pf(10000.0f);
  int r = (dist > q1 ? 1 : 0) + (dist > q2 ? 1 : 0);
  et[e] = r;
  int s = ei[e], d = ei[NE + e];
  atomicAdd(&cntR[d * 3 + r], 1);
  #pragma unroll
  for (int k = 0; k < 3; k++)
    atomicAdd(&agg0[d * 9 + r * 3 + k], x[s * 3 + k]);
}

// ---------------- CSR build: block sums -> scan of block sums -> offsets/dinv -> scatter ----
__global__ __launch_bounds__(256) void scanA(const int* __restrict__ cntR, int* __restrict__ bsum) {
  __shared__ int sd[256];
  int n = blockIdx.x * 256 + threadIdx.x;
  int deg = 0;
  if (n < NN) deg = cntR[3 * n] + cntR[3 * n + 1] + cntR[3 * n + 2];
  sd[threadIdx.x] = deg;
  __syncthreads();
  #pragma unroll
  for (int s = 128; s > 0; s >>= 1) {
    if (threadIdx.x < s) sd[threadIdx.x] += sd[threadIdx.x + s];
    __syncthreads();
  }
  if (threadIdx.x == 0) bsum[blockIdx.x] = sd[0];
}

__global__ __launch_bounds__(256) void scanB(int* __restrict__ bsum) {
  __shared__ int sd[256];
  int v = (threadIdx.x < NB) ? bsum[threadIdx.x] : 0;
  sd[threadIdx.x] = v;
  __syncthreads();
  for (int s = 1; s < 256; s <<= 1) {
    int t = (threadIdx.x >= s) ? sd[threadIdx.x - s] : 0;
    __syncthreads();
    sd[threadIdx.x] += t;
    __syncthreads();
  }
  if (threadIdx.x < NB) bsum[threadIdx.x] = sd[threadIdx.x] - v;  // exclusive
}

__global__ __launch_bounds__(256) void scanC(
    const int* __restrict__ cntR, const int* __restrict__ bsum,
    int* __restrict__ off, int* __restrict__ cursor, int* __restrict__ degA,
    float* __restrict__ dinv)
{
  __shared__ int sd[256];
  int n = blockIdx.x * 256 + threadIdx.x;
  int c0 = 0, c1 = 0, c2 = 0;
  if (n < NN) { c0 = cntR[3 * n]; c1 = cntR[3 * n + 1]; c2 = cntR[3 * n + 2]; }
  int deg = c0 + c1 + c2;
  sd[threadIdx.x] = deg;
  __syncthreads();
  for (int s = 1; s < 256; s <<= 1) {
    int t = (threadIdx.x >= s) ? sd[threadIdx.x - s] : 0;
    __syncthreads();
    sd[threadIdx.x] += t;
    __syncthreads();
  }
  if (n < NN) {
    int o = bsum[blockIdx.x] + sd[threadIdx.x] - deg;
    off[n] = o; cursor[n] = o; degA[n] = deg;
    dinv[3 * n + 0] = 1.0f / (float)(c0 > 1 ? c0 : 1);
    dinv[3 * n + 1] = 1.0f / (float)(c1 > 1 ? c1 : 1);
    dinv[3 * n + 2] = 1.0f / (float)(c2 > 1 ? c2 : 1);
  }
}

__global__ __launch_bounds__(256) void scatter_kernel(
    const int* __restrict__ ei, const int* __restrict__ et,
    int* __restrict__ cursor, int* __restrict__ sorted)
{
  int e = blockIdx.x * blockDim.x + threadIdx.x;
  if (e >= NE) return;
  int s = ei[e], d = ei[NE + e], r = et[e];
  int pos = atomicAdd(&cursor[d], 1);
  sorted[pos] = (r << 16) | s;
}

// ---------------- CSR aggregation: one wave per node, plain stores ----------------
__global__ __launch_bounds__(256) void agg_csr(
    const float* __restrict__ hin, const int* __restrict__ off, const int* __restrict__ degA,
    const int* __restrict__ sorted, float* __restrict__ agg)
{
  int wid = (blockIdx.x * blockDim.x + threadIdx.x) >> 6;
  int lane = threadIdx.x & 63;
  if (wid >= NN) return;
  int start = off[wid], deg = degA[wid];
  float a0 = 0.f, a1 = 0.f, a2 = 0.f;
  for (int base = 0; base < deg; base += 64) {
    int cnt = deg - base; if (cnt > 64) cnt = 64;
    int ent = (lane < cnt) ? sorted[start + base + lane] : 0;
    for (int j = 0; j < cnt; j++) {
      int e = __shfl(ent, j, 64);
      int s = e & 0xFFFF;
      int r = e >> 16;
      float v = hin[s * HD + lane];
      if (r == 0) a0 += v; else if (r == 1) a1 += v; else a2 += v;
    }
  }
  float* p = agg + wid * 192 + lane;
  p[0] = a0; p[64] = a1; p[128] = a2;
}

// ---------------- layer 0 node update (IN=3) + relu + residual + LN ----------------
__global__ __launch_bounds__(256) void node0_kernel(
    const float* __restrict__ x, const float* __restrict__ agg0, const float* __restrict__ dinv,
    const float* __restrict__ w0, const float* __restrict__ root0, const float* __restrict__ b0,
    const float* __restrict__ res_w, const float* __restrict__ res_b,
    const float* __restrict__ g, const float* __restrict__ bb, float* __restrict__ h1)
{
  int wid = __builtin_amdgcn_readfirstlane((int)((blockIdx.x * blockDim.x + threadIdx.x) >> 6));
  int lane = threadIdx.x & 63;
  int n0 = wid * 8;
  if (n0 >= NN) return;
  float wr[3], ww[9], wres[3];
  #pragma unroll
  for (int i = 0; i < 3; i++) { wr[i] = root0[i * HD + lane]; wres[i] = res_w[i * HD + lane]; }
  #pragma unroll
  for (int i = 0; i < 9; i++) ww[i] = w0[i * HD + lane];
  float vb = b0[lane], vrb = res_b[lane], vg = g[lane], vbb = bb[lane];
  #pragma unroll
  for (int k = 0; k < 8; k++) {
    int nk = n0 + k;
    float xv[3];
    #pragma unroll
    for (int i = 0; i < 3; i++) xv[i] = x[nk * 3 + i];
    float v = vb;
    #pragma unroll
    for (int i = 0; i < 3; i++) v = fmaf(xv[i], wr[i], v);
    #pragma unroll
    for (int r = 0; r < 3; r++) {
      float s = 0.f;
      #pragma unroll
      for (int i = 0; i < 3; i++) s = fmaf(agg0[nk * 9 + r * 3 + i], ww[r * 3 + i], s);
      v = fmaf(dinv[nk * 3 + r], s, v);
    }
    v = fmaxf(v, 0.f);
    float res = vrb;
    #pragma unroll
    for (int i = 0; i < 3; i++) res = fmaf(xv[i], wres[i], res);
    float t = v + res;
    float mu = wave_sum(t) * 0.015625f;
    float dt = t - mu;
    float var = wave_sum(dt * dt) * 0.015625f;
    h1[nk * HD + lane] = dt * rsqrtf(var + 1e-5f) * vg + vbb;
  }
}

// ---------------- H->H node update + relu + residual + LN ----------------
__global__ __launch_bounds__(256) void node_hh(
    const float* __restrict__ hin, const float* __restrict__ agg, const float* __restrict__ dinv,
    const float* __restrict__ W, const float* __restrict__ root, const float* __restrict__ bias,
    const float* __restrict__ g, const float* __restrict__ bb, float* __restrict__ hout)
{
  int wid = __builtin_amdgcn_readfirstlane((int)((blockIdx.x * blockDim.x + threadIdx.x) >> 6));
  int lane = threadIdx.x & 63;
  int n0 = wid * 8;
  if (n0 >= NN) return;
  float accR[8], accA0[8], accA1[8], accA2[8];
  #pragma unroll
  for (int k = 0; k < 8; k++) { accR[k] = 0.f; accA0[k] = 0.f; accA1[k] = 0.f; accA2[k] = 0.f; }
  #pragma unroll 4
  for (int i = 0; i < HD; i++) {
    float wr  = root[i * HD + lane];
    float wa0 = W[i * HD + lane];
    float wa1 = W[4096 + i * HD + lane];
    float wa2 = W[8192 + i * HD + lane];
    #pragma unroll
    for (int k = 0; k < 8; k++) {
      int nk = n0 + k;
      accR[k]  = fmaf(hin[nk * HD + i],        wr,  accR[k]);
      accA0[k] = fmaf(agg[nk * 192 + i],       wa0, accA0[k]);
      accA1[k] = fmaf(agg[nk * 192 + 64 + i],  wa1, accA1[k]);
      accA2[k] = fmaf(agg[nk * 192 + 128 + i], wa2, accA2[k]);
    }
  }
  float vb = bias[lane], vg = g[lane], vbb = bb[lane];
  #pragma unroll
  for (int k = 0; k < 8; k++) {
    int nk = n0 + k;
    float v = vb + accR[k];
    v = fmaf(dinv[nk * 3 + 0], accA0[k], v);
    v = fmaf(dinv[nk * 3 + 1], accA1[k], v);
    v = fmaf(dinv[nk * 3 + 2], accA2[k], v);
    v = fmaxf(v, 0.f);
    float t = v + hin[nk * HD + lane];
    float mu = wave_sum(t) * 0.015625f;
    float dt = t - mu;
    float var = wave_sum(dt * dt) * 0.015625f;
    hout[nk * HD + lane] = dt * rsqrtf(var + 1e-5f) * vg + vbb;
  }
}

// ---------------- per-edge decoder MLP ----------------
__global__ __launch_bounds__(256) void decoder_kernel(
    const float* __restrict__ h3, const int* __restrict__ ei, const float* __restrict__ ea,
    const float* __restrict__ W1, const float* __restrict__ B1,
    const float* __restrict__ W2, const float* __restrict__ B2,
    const float* __restrict__ W3, const float* __restrict__ B3,
    float* __restrict__ out)
{
  int e = blockIdx.x * blockDim.x + threadIdx.x;
  if (e >= NE) return;
  int s = ei[e], d = ei[NE + e];
  const float4* hs4 = (const float4*)(h3 + s * HD);
  const float4* hd4 = (const float4*)(h3 + d * HD);
  float z[32];
  #pragma unroll
  for (int o = 0; o < 32; o++) z[o] = B1[o];
  for (int j4 = 0; j4 < 16; j4++) {
    float4 a = hs4[j4], b = hd4[j4];
    float fa[4] = {a.x, a.y, a.z, a.w};
    float fb[4] = {b.x, b.y, b.z, b.w};
    #pragma unroll
    for (int jj = 0; jj < 4; jj++) {
      int j = j4 * 4 + jj;
      float va = fa[jj], vbv = fb[jj];
      float vab = fabsf(va - vbv), vm = va * vbv;
      const float* w1a = W1 + j * 32;
      const float* w1b = W1 + (64 + j) * 32;
      const float* w1c = W1 + (128 + j) * 32;
      const float* w1d = W1 + (192 + j) * 32;
      #pragma unroll
      for (int o = 0; o < 32; o++) {
        float acc = z[o];
        acc = fmaf(va, w1a[o], acc);
        acc = fmaf(vbv, w1b[o], acc);
        acc = fmaf(vab, w1c[o], acc);
        acc = fmaf(vm, w1d[o], acc);
        z[o] = acc;
      }
    }
  }
  #pragma unroll
  for (int k = 0; k < 6; k++) {
    float v = ea[e * 6 + k];
    const float* wk = W1 + (256 + k) * 32;
    #pragma unroll
    for (int o = 0; o < 32; o++) z[o] = fmaf(v, wk[o], z[o]);
  }
  float z2[16];
  #pragma unroll
  for (int p = 0; p < 16; p++) z2[p] = B2[p];
  #pragma unroll
  for (int o = 0; o < 32; o++) {
    float v = fmaxf(z[o], 0.f);
    #pragma unroll
    for (int p = 0; p < 16; p++) z2[p] = fmaf(v, W2[o * 16 + p], z2[p]);
  }
  float r = B3[0];
  #pragma unroll
  for (int p = 0; p < 16; p++) r = fmaf(fmaxf(z2[p], 0.f), W3[p], r);
  out[e] = r;
}

extern "C" void kernel_launch(void* const* d_in, const int* in_sizes, int n_in,
                              void* d_out, int out_size, void* d_ws, size_t ws_size,
                              hipStream_t stream) {
  const float* x      = (const float*)d_in[0];
  const int*   ei     = (const int*)d_in[1];
  const float* ea     = (const float*)d_in[2];
  const float* w0     = (const float*)d_in[3];
  const float* root0  = (const float*)d_in[4];
  const float* b0     = (const float*)d_in[5];
  const float* w1     = (const float*)d_in[6];
  const float* root1  = (const float*)d_in[7];
  const float* b1     = (const float*)d_in[8];
  const float* w2     = (const float*)d_in[9];
  const float* root2  = (const float*)d_in[10];
  const float* b2     = (const float*)d_in[11];
  const float* ln_g0  = (const float*)d_in[12];
  const float* ln_b0  = (const float*)d_in[13];
  const float* ln_g1  = (const float*)d_in[14];
  const float* ln_b1  = (const float*)d_in[15];
  const float* ln_g2  = (const float*)d_in[16];
  const float* ln_b2  = (const float*)d_in[17];
  const float* res_w  = (const float*)d_in[18];
  const float* res_b  = (const float*)d_in[19];
  const float* dec_w1 = (const float*)d_in[20];
  const float* dec_b1 = (const float*)d_in[21];
  const float* dec_w2 = (const float*)d_in[22];
  const float* dec_b2 = (const float*)d_in[23];
  const float* dec_w3 = (const float*)d_in[24];
  const float* dec_b3 = (const float*)d_in[25];

  char* ws = (char*)d_ws;
  int*   et     = (int*)(ws + 0);             //  3,200,000 B
  int*   cntR   = (int*)(ws + 3200000);       //    600,000 B  (memset 0)
  float* agg0   = (float*)(ws + 3800000);     //  1,800,000 B  (memset 0)
  int*   bsum   = (int*)(ws + 5600000);       //      1,024 B
  int*   off    = (int*)(ws + 5601024);       //    200,000 B
  int*   cursor = (int*)(ws + 5801024);       //    200,000 B
  int*   degA   = (int*)(ws + 6001024);       //    200,000 B
  float* dinv   = (float*)(ws + 6201024);     //    600,000 B
  int*   sorted = (int*)(ws + 6801024);       //  3,200,000 B
  float* agg    = (float*)(ws + 10001024);    // 38,400,000 B
  float* h1     = (float*)(ws + 48401024);    // 12,800,000 B
  float* h2     = (float*)(ws + 61201024);    // 12,800,000 B
  float* h3     = h1;                         // h1 dead after layer-1 update; alias

  hipMemsetAsync(cntR, 0, 600000 + 1800000, stream);  // cntR + agg0 contiguous

  edge_prep<<<(NE + 255) / 256, 256, 0, stream>>>(ei, ea, x, et, cntR, agg0);
  scanA<<<NB, 256, 0, stream>>>(cntR, bsum);
  scanB<<<1, 256, 0, stream>>>(bsum);
  scanC<<<NB, 256, 0, stream>>>(cntR, bsum, off, cursor, degA, dinv);
  scatter_kernel<<<(NE + 255) / 256, 256, 0, stream>>>(ei, et, cursor, sorted);

  const int node_blocks = (NN / 8 + 3) / 4;   // 8 nodes/wave, 4 waves/block
  const int agg_blocks  = (NN + 3) / 4;       // 1 node/wave, 4 waves/block

  node0_kernel<<<node_blocks, 256, 0, stream>>>(x, agg0, dinv, w0, root0, b0,
                                                res_w, res_b, ln_g0, ln_b0, h1);

  agg_csr<<<agg_blocks, 256, 0, stream>>>(h1, off, degA, sorted, agg);
  node_hh<<<node_blocks, 256, 0, stream>>>(h1, agg, dinv, w1, root1, b1, ln_g1, ln_b1, h2);

  agg_csr<<<agg_blocks, 256, 0, stream>>>(h2, off, degA, sorted, agg);
  node_hh<<<node_blocks, 256, 0, stream>>>(h2, agg, dinv, w2, root2, b2, ln_g2, ln_b2, h3);

  decoder_kernel<<<(NE + 255) / 256, 256, 0, stream>>>(h3, ei, ea, dec_w1, dec_b1,
                                                       dec_w2, dec_b2, dec_w3, dec_b3,
                                                       (float*)d_out);
}

// Round 3
// 744.677 us; speedup vs baseline: 2.9021x; 1.1482x over previous
//
#include <hip/hip_runtime.h>
#include <math.h>

#define NN 50000
#define NE 800000
#define HD 64
#define NB 196  // ceil(50000/256)

typedef float f32x4 __attribute__((ext_vector_type(4)));
typedef short short8 __attribute__((ext_vector_type(8)));

__device__ __forceinline__ float wave_sum(float v) {
  #pragma unroll
  for (int off = 32; off > 0; off >>= 1) v += __shfl_xor(v, off, 64);
  return v;
}

__device__ __forceinline__ unsigned short f2bf(float f) {
  union { float f; unsigned u; } v; v.f = f;
  unsigned r = v.u + 0x7FFF + ((v.u >> 16) & 1);  // RNE
  return (unsigned short)(r >> 16);
}
__device__ __forceinline__ float bf2f(unsigned short b) {
  union { unsigned u; float f; } v; v.u = ((unsigned)b) << 16;
  return v.f;
}

// ---------------- edge prep: edge_type + per-(dst,rel) histogram + layer0 agg ----------------
__global__ __launch_bounds__(256) void edge_prep(
    const int* __restrict__ ei, const float* __restrict__ ea, const float* __restrict__ x,
    int* __restrict__ et, int* __restrict__ cntR, float* __restrict__ agg0)
{
  int e = blockIdx.x * blockDim.x + threadIdx.x;
  if (e >= NE) return;
  float dist = ea[e * 6];
  const float q1 = log1pf(5000.0f);
  const float q2 = log1pf(10000.0f);
  int r = (dist > q1 ? 1 : 0) + (dist > q2 ? 1 : 0);
  et[e] = r;
  int s = ei[e], d = ei[NE + e];
  atomicAdd(&cntR[d * 3 + r], 1);
  #pragma unroll
  for (int k = 0; k < 3; k++)
    atomicAdd(&agg0[d * 9 + r * 3 + k], x[s * 3 + k]);
}

// ---------------- CSR build ----------------
__global__ __launch_bounds__(256) void scanA(const int* __restrict__ cntR, int* __restrict__ bsum) {
  __shared__ int sd[256];
  int n = blockIdx.x * 256 + threadIdx.x;
  int deg = 0;
  if (n < NN) deg = cntR[3 * n] + cntR[3 * n + 1] + cntR[3 * n + 2];
  sd[threadIdx.x] = deg;
  __syncthreads();
  #pragma unroll
  for (int s = 128; s > 0; s >>= 1) {
    if (threadIdx.x < s) sd[threadIdx.x] += sd[threadIdx.x + s];
    __syncthreads();
  }
  if (threadIdx.x == 0) bsum[blockIdx.x] = sd[0];
}

__global__ __launch_bounds__(256) void scanB(int* __restrict__ bsum) {
  __shared__ int sd[256];
  int v = (threadIdx.x < NB) ? bsum[threadIdx.x] : 0;
  sd[threadIdx.x] = v;
  __syncthreads();
  for (int s = 1; s < 256; s <<= 1) {
    int t = (threadIdx.x >= s) ? sd[threadIdx.x - s] : 0;
    __syncthreads();
    sd[threadIdx.x] += t;
    __syncthreads();
  }
  if (threadIdx.x < NB) bsum[threadIdx.x] = sd[threadIdx.x] - v;  // exclusive
}

__global__ __launch_bounds__(256) void scanC(
    const int* __restrict__ cntR, const int* __restrict__ bsum,
    int* __restrict__ off, int* __restrict__ cursor, int* __restrict__ degA,
    float* __restrict__ dinv)
{
  __shared__ int sd[256];
  int n = blockIdx.x * 256 + threadIdx.x;
  int c0 = 0, c1 = 0, c2 = 0;
  if (n < NN) { c0 = cntR[3 * n]; c1 = cntR[3 * n + 1]; c2 = cntR[3 * n + 2]; }
  int deg = c0 + c1 + c2;
  sd[threadIdx.x] = deg;
  __syncthreads();
  for (int s = 1; s < 256; s <<= 1) {
    int t = (threadIdx.x >= s) ? sd[threadIdx.x - s] : 0;
    __syncthreads();
    sd[threadIdx.x] += t;
    __syncthreads();
  }
  if (n < NN) {
    int o = bsum[blockIdx.x] + sd[threadIdx.x] - deg;
    off[n] = o; cursor[n] = o; degA[n] = deg;
    dinv[3 * n + 0] = 1.0f / (float)(c0 > 1 ? c0 : 1);
    dinv[3 * n + 1] = 1.0f / (float)(c1 > 1 ? c1 : 1);
    dinv[3 * n + 2] = 1.0f / (float)(c2 > 1 ? c2 : 1);
  }
}

__global__ __launch_bounds__(256) void scatter_kernel(
    const int* __restrict__ ei, const int* __restrict__ et,
    int* __restrict__ cursor, int* __restrict__ sorted)
{
  int e = blockIdx.x * blockDim.x + threadIdx.x;
  if (e >= NE) return;
  int s = ei[e], d = ei[NE + e], r = et[e];
  int pos = atomicAdd(&cursor[d], 1);
  sorted[pos] = (r << 16) | s;
}

// ---------------- pack W1 (first 256 rows) into MFMA B-fragment order, bf16 ------------------
// pk[((t*2+nt)*64 + lane)*8 + j] = W1[(t*32 + (lane>>4)*8 + j)*32 + nt*16 + (lane&15)]
__global__ __launch_bounds__(256) void pack_w1(const float* __restrict__ W1, unsigned short* __restrict__ pk) {
  for (int idx = threadIdx.x; idx < 8192; idx += 256) {
    int j = idx & 7, l = (idx >> 3) & 63, nt = (idx >> 9) & 1, t = idx >> 10;
    int k = t * 32 + (l >> 4) * 8 + j;
    int n = nt * 16 + (l & 15);
    pk[idx] = f2bf(W1[k * 32 + n]);
  }
}

// ---------------- CSR aggregation: one wave per node, plain stores ----------------
__global__ __launch_bounds__(256) void agg_csr(
    const float* __restrict__ hin, const int* __restrict__ off, const int* __restrict__ degA,
    const int* __restrict__ sorted, float* __restrict__ agg)
{
  int wid = (blockIdx.x * blockDim.x + threadIdx.x) >> 6;
  int lane = threadIdx.x & 63;
  if (wid >= NN) return;
  int start = off[wid], deg = degA[wid];
  float a0 = 0.f, a1 = 0.f, a2 = 0.f;
  for (int base = 0; base < deg; base += 64) {
    int cnt = deg - base; if (cnt > 64) cnt = 64;
    int ent = (lane < cnt) ? sorted[start + base + lane] : 0;
    for (int j = 0; j < cnt; j++) {
      int e = __shfl(ent, j, 64);
      int s = e & 0xFFFF;
      int r = e >> 16;
      float v = hin[s * HD + lane];
      if (r == 0) a0 += v; else if (r == 1) a1 += v; else a2 += v;
    }
  }
  float* p = agg + wid * 192 + lane;
  p[0] = a0; p[64] = a1; p[128] = a2;
}

// ---------------- layer 0 node update (IN=3) + relu + residual + LN ----------------
__global__ __launch_bounds__(256) void node0_kernel(
    const float* __restrict__ x, const float* __restrict__ agg0, const float* __restrict__ dinv,
    const float* __restrict__ w0, const float* __restrict__ root0, const float* __restrict__ b0,
    const float* __restrict__ res_w, const float* __restrict__ res_b,
    const float* __restrict__ g, const float* __restrict__ bb, float* __restrict__ h1)
{
  int wid = __builtin_amdgcn_readfirstlane((int)((blockIdx.x * blockDim.x + threadIdx.x) >> 6));
  int lane = threadIdx.x & 63;
  int n0 = wid * 8;
  if (n0 >= NN) return;
  float wr[3], ww[9], wres[3];
  #pragma unroll
  for (int i = 0; i < 3; i++) { wr[i] = root0[i * HD + lane]; wres[i] = res_w[i * HD + lane]; }
  #pragma unroll
  for (int i = 0; i < 9; i++) ww[i] = w0[i * HD + lane];
  float vb = b0[lane], vrb = res_b[lane], vg = g[lane], vbb = bb[lane];
  #pragma unroll
  for (int k = 0; k < 8; k++) {
    int nk = n0 + k;
    float xv[3];
    #pragma unroll
    for (int i = 0; i < 3; i++) xv[i] = x[nk * 3 + i];
    float v = vb;
    #pragma unroll
    for (int i = 0; i < 3; i++) v = fmaf(xv[i], wr[i], v);
    #pragma unroll
    for (int r = 0; r < 3; r++) {
      float s = 0.f;
      #pragma unroll
      for (int i = 0; i < 3; i++) s = fmaf(agg0[nk * 9 + r * 3 + i], ww[r * 3 + i], s);
      v = fmaf(dinv[nk * 3 + r], s, v);
    }
    v = fmaxf(v, 0.f);
    float res = vrb;
    #pragma unroll
    for (int i = 0; i < 3; i++) res = fmaf(xv[i], wres[i], res);
    float t = v + res;
    float mu = wave_sum(t) * 0.015625f;
    float dt = t - mu;
    float var = wave_sum(dt * dt) * 0.015625f;
    h1[nk * HD + lane] = dt * rsqrtf(var + 1e-5f) * vg + vbb;
  }
}

// ---------------- H->H node update + relu + residual + LN (fp32 and/or bf16 out) -------------
__global__ __launch_bounds__(256) void node_hh(
    const float* __restrict__ hin, const float* __restrict__ agg, const float* __restrict__ dinv,
    const float* __restrict__ W, const float* __restrict__ root, const float* __restrict__ bias,
    const float* __restrict__ g, const float* __restrict__ bb,
    float* __restrict__ hout, unsigned short* __restrict__ hout_b)
{
  int wid = __builtin_amdgcn_readfirstlane((int)((blockIdx.x * blockDim.x + threadIdx.x) >> 6));
  int lane = threadIdx.x & 63;
  int n0 = wid * 8;
  if (n0 >= NN) return;
  float accR[8], accA0[8], accA1[8], accA2[8];
  #pragma unroll
  for (int k = 0; k < 8; k++) { accR[k] = 0.f; accA0[k] = 0.f; accA1[k] = 0.f; accA2[k] = 0.f; }
  #pragma unroll 4
  for (int i = 0; i < HD; i++) {
    float wr  = root[i * HD + lane];
    float wa0 = W[i * HD + lane];
    float wa1 = W[4096 + i * HD + lane];
    float wa2 = W[8192 + i * HD + lane];
    #pragma unroll
    for (int k = 0; k < 8; k++) {
      int nk = n0 + k;
      accR[k]  = fmaf(hin[nk * HD + i],        wr,  accR[k]);
      accA0[k] = fmaf(agg[nk * 192 + i],       wa0, accA0[k]);
      accA1[k] = fmaf(agg[nk * 192 + 64 + i],  wa1, accA1[k]);
      accA2[k] = fmaf(agg[nk * 192 + 128 + i], wa2, accA2[k]);
    }
  }
  float vb = bias[lane], vg = g[lane], vbb = bb[lane];
  #pragma unroll
  for (int k = 0; k < 8; k++) {
    int nk = n0 + k;
    float v = vb + accR[k];
    v = fmaf(dinv[nk * 3 + 0], accA0[k], v);
    v = fmaf(dinv[nk * 3 + 1], accA1[k], v);
    v = fmaf(dinv[nk * 3 + 2], accA2[k], v);
    v = fmaxf(v, 0.f);
    float t = v + hin[nk * HD + lane];
    float mu = wave_sum(t) * 0.015625f;
    float dt = t - mu;
    float var = wave_sum(dt * dt) * 0.015625f;
    float o = dt * rsqrtf(var + 1e-5f) * vg + vbb;
    if (hout)   hout[nk * HD + lane] = o;
    if (hout_b) hout_b[nk * HD + lane] = f2bf(o);
  }
}

// ---------------- decoder: 16 edges/wave, bf16 MFMA for the 262x32 layer ----------------
__global__ __launch_bounds__(256) void decoder_mfma(
    const unsigned short* __restrict__ h3b, const int* __restrict__ ei, const float* __restrict__ ea,
    const unsigned short* __restrict__ pk, const float* __restrict__ W1f, const float* __restrict__ B1,
    const float* __restrict__ W2, const float* __restrict__ B2,
    const float* __restrict__ W3, const float* __restrict__ B3,
    float* __restrict__ out)
{
  __shared__ float lds[4 * 16 * 33];
  int wv = threadIdx.x >> 6;
  int lane = threadIdx.x & 63;
  int e0 = (blockIdx.x * 4 + wv) * 16;
  int m = lane & 15, g = lane >> 4;

  int s = ei[e0 + m], d = ei[NE + e0 + m];
  const short8* ps = (const short8*)(h3b + (size_t)s * HD + g * 8);
  const short8* pd = (const short8*)(h3b + (size_t)d * HD + g * 8);
  short8 hs0 = ps[0];
  short8 hs1 = *(const short8*)(h3b + (size_t)s * HD + 32 + g * 8);
  short8 hd0 = pd[0];
  short8 hd1 = *(const short8*)(h3b + (size_t)d * HD + 32 + g * 8);

  short8 ad0, ad1, pd0, pd1;
  #pragma unroll
  for (int j = 0; j < 8; j++) {
    float a0 = bf2f((unsigned short)hs0[j]), b0 = bf2f((unsigned short)hd0[j]);
    float a1 = bf2f((unsigned short)hs1[j]), b1 = bf2f((unsigned short)hd1[j]);
    ad0[j] = (short)f2bf(fabsf(a0 - b0));
    ad1[j] = (short)f2bf(fabsf(a1 - b1));
    pd0[j] = (short)f2bf(a0 * b0);
    pd1[j] = (short)f2bf(a1 * b1);
  }

  short8 A[8] = {hs0, hs1, hd0, hd1, ad0, ad1, pd0, pd1};
  const short8* pkv = (const short8*)pk;
  f32x4 acc0 = {0.f, 0.f, 0.f, 0.f};
  f32x4 acc1 = {0.f, 0.f, 0.f, 0.f};
  #pragma unroll
  for (int t = 0; t < 8; t++) {
    acc0 = __builtin_amdgcn_mfma_f32_16x16x32_bf16(A[t], pkv[(t * 2 + 0) * 64 + lane], acc0, 0, 0, 0);
    acc1 = __builtin_amdgcn_mfma_f32_16x16x32_bf16(A[t], pkv[(t * 2 + 1) * 64 + lane], acc1, 0, 0, 0);
  }

  // epilogue phase 1: bias + edge_attr tail (fp32) + relu -> LDS (stride 33)
  int cn = lane & 15;  // output column
  float wt0[6], wt1[6];
  #pragma unroll
  for (int k = 0; k < 6; k++) {
    wt0[k] = W1f[(256 + k) * 32 + cn];
    wt1[k] = W1f[(256 + k) * 32 + 16 + cn];
  }
  float b1a = B1[cn], b1b = B1[16 + cn];
  float* Z = lds + wv * 528;
  #pragma unroll
  for (int r = 0; r < 4; r++) {
    int mr = g * 4 + r;
    float z0 = acc0[r] + b1a;
    float z1 = acc1[r] + b1b;
    #pragma unroll
    for (int k = 0; k < 6; k++) {
      float eav = ea[(size_t)(e0 + mr) * 6 + k];
      z0 = fmaf(eav, wt0[k], z0);
      z1 = fmaf(eav, wt1[k], z1);
    }
    Z[mr * 33 + cn] = fmaxf(z0, 0.f);
    Z[mr * 33 + 16 + cn] = fmaxf(z1, 0.f);
  }
  // wave-private LDS: no barrier needed (compiler inserts lgkmcnt wait)

  // epilogue phase 2: z2 (16) in 4 lanes/edge, then z3 + shuffle reduce
  int me = lane & 15, q = g;
  float z2[4];
  #pragma unroll
  for (int p = 0; p < 4; p++) z2[p] = B2[q * 4 + p];
  #pragma unroll 8
  for (int n = 0; n < 32; n++) {
    float zv = Z[me * 33 + n];
    const float4 w2v = *(const float4*)(W2 + n * 16 + q * 4);
    z2[0] = fmaf(zv, w2v.x, z2[0]);
    z2[1] = fmaf(zv, w2v.y, z2[1]);
    z2[2] = fmaf(zv, w2v.z, z2[2]);
    z2[3] = fmaf(zv, w2v.w, z2[3]);
  }
  const float4 w3v = *(const float4*)(W3 + q * 4);
  float part = fmaxf(z2[0], 0.f) * w3v.x + fmaxf(z2[1], 0.f) * w3v.y +
               fmaxf(z2[2], 0.f) * w3v.z + fmaxf(z2[3], 0.f) * w3v.w;
  part += __shfl_xor(part, 16, 64);
  part += __shfl_xor(part, 32, 64);
  if (g == 0) out[e0 + me] = part + B3[0];
}

extern "C" void kernel_launch(void* const* d_in, const int* in_sizes, int n_in,
                              void* d_out, int out_size, void* d_ws, size_t ws_size,
                              hipStream_t stream) {
  const float* x      = (const float*)d_in[0];
  const int*   ei     = (const int*)d_in[1];
  const float* ea     = (const float*)d_in[2];
  const float* w0     = (const float*)d_in[3];
  const float* root0  = (const float*)d_in[4];
  const float* b0     = (const float*)d_in[5];
  const float* w1     = (const float*)d_in[6];
  const float* root1  = (const float*)d_in[7];
  const float* b1     = (const float*)d_in[8];
  const float* w2     = (const float*)d_in[9];
  const float* root2  = (const float*)d_in[10];
  const float* b2     = (const float*)d_in[11];
  const float* ln_g0  = (const float*)d_in[12];
  const float* ln_b0  = (const float*)d_in[13];
  const float* ln_g1  = (const float*)d_in[14];
  const float* ln_b1  = (const float*)d_in[15];
  const float* ln_g2  = (const float*)d_in[16];
  const float* ln_b2  = (const float*)d_in[17];
  const float* res_w  = (const float*)d_in[18];
  const float* res_b  = (const float*)d_in[19];
  const float* dec_w1 = (const float*)d_in[20];
  const float* dec_b1 = (const float*)d_in[21];
  const float* dec_w2 = (const float*)d_in[22];
  const float* dec_b2 = (const float*)d_in[23];
  const float* dec_w3 = (const float*)d_in[24];
  const float* dec_b3 = (const float*)d_in[25];

  char* ws = (char*)d_ws;
  int*   et     = (int*)(ws + 0);             //  3,200,000 B
  int*   cntR   = (int*)(ws + 3200000);       //    600,000 B  (memset 0)
  float* agg0   = (float*)(ws + 3800000);     //  1,800,000 B  (memset 0)
  int*   bsum   = (int*)(ws + 5600000);       //      1,024 B
  int*   off    = (int*)(ws + 5601024);       //    200,000 B
  int*   cursor = (int*)(ws + 5801024);       //    200,000 B
  int*   degA   = (int*)(ws + 6001024);       //    200,000 B
  float* dinv   = (float*)(ws + 6201024);     //    600,000 B
  int*   sorted = (int*)(ws + 6801024);       //  3,200,000 B
  float* agg    = (float*)(ws + 10001024);    // 38,400,000 B
  float* h1     = (float*)(ws + 48401024);    // 12,800,000 B
  float* h2     = (float*)(ws + 61201024);    // 12,800,000 B
  unsigned short* h3b = (unsigned short*)(ws + 74001024);  // 6,400,000 B
  unsigned short* pkw = (unsigned short*)(ws + 80401024);  //    16,384 B  (end 80,417,408)

  hipMemsetAsync(cntR, 0, 600000 + 1800000, stream);  // cntR + agg0 contiguous

  edge_prep<<<(NE + 255) / 256, 256, 0, stream>>>(ei, ea, x, et, cntR, agg0);
  scanA<<<NB, 256, 0, stream>>>(cntR, bsum);
  scanB<<<1, 256, 0, stream>>>(bsum);
  scanC<<<NB, 256, 0, stream>>>(cntR, bsum, off, cursor, degA, dinv);
  scatter_kernel<<<(NE + 255) / 256, 256, 0, stream>>>(ei, et, cursor, sorted);
  pack_w1<<<1, 256, 0, stream>>>(dec_w1, pkw);

  const int node_blocks = (NN / 8 + 3) / 4;   // 8 nodes/wave, 4 waves/block
  const int agg_blocks  = (NN + 3) / 4;       // 1 node/wave, 4 waves/block

  node0_kernel<<<node_blocks, 256, 0, stream>>>(x, agg0, dinv, w0, root0, b0,
                                                res_w, res_b, ln_g0, ln_b0, h1);

  agg_csr<<<agg_blocks, 256, 0, stream>>>(h1, off, degA, sorted, agg);
  node_hh<<<node_blocks, 256, 0, stream>>>(h1, agg, dinv, w1, root1, b1, ln_g1, ln_b1, h2, nullptr);

  agg_csr<<<agg_blocks, 256, 0, stream>>>(h2, off, degA, sorted, agg);
  node_hh<<<node_blocks, 256, 0, stream>>>(h2, agg, dinv, w2, root2, b2, ln_g2, ln_b2, nullptr, h3b);

  decoder_mfma<<<NE / 64, 256, 0, stream>>>(h3b, ei, ea, pkw, dec_w1, dec_b1,
                                            dec_w2, dec_b2, dec_w3, dec_b3, (float*)d_out);
}

// Round 4
// 650.415 us; speedup vs baseline: 3.3226x; 1.1449x over previous
//
#include <hip/hip_runtime.h>
#include <math.h>

#define NN 50000
#define NE 800000
#define HD 64
#define NB 196  // ceil(50000/256)

typedef float f32x4 __attribute__((ext_vector_type(4)));
typedef short short8 __attribute__((ext_vector_type(8)));

__device__ __forceinline__ float wave_sum(float v) {
  #pragma unroll
  for (int off = 32; off > 0; off >>= 1) v += __shfl_xor(v, off, 64);
  return v;
}

__device__ __forceinline__ unsigned short f2bf(float f) {
  union { float f; unsigned u; } v; v.f = f;
  unsigned r = v.u + 0x7FFF + ((v.u >> 16) & 1);  // RNE
  return (unsigned short)(r >> 16);
}
__device__ __forceinline__ float bf2f(unsigned short b) {
  union { unsigned u; float f; } v; v.u = ((unsigned)b) << 16;
  return v.f;
}

// ---------------- edge prep: edge_type + per-(dst,rel) histogram ONLY ----------------
__global__ __launch_bounds__(256) void edge_prep(
    const int* __restrict__ ei, const float* __restrict__ ea,
    int* __restrict__ et, int* __restrict__ cntR)
{
  int e = blockIdx.x * blockDim.x + threadIdx.x;
  if (e >= NE) return;
  float dist = ea[e * 6];
  const float q1 = log1pf(5000.0f);
  const float q2 = log1pf(10000.0f);
  int r = (dist > q1 ? 1 : 0) + (dist > q2 ? 1 : 0);
  et[e] = r;
  int d = ei[NE + e];
  atomicAdd(&cntR[d * 3 + r], 1);
}

// ---------------- CSR build ----------------
__global__ __launch_bounds__(256) void scanA(const int* __restrict__ cntR, int* __restrict__ bsum) {
  __shared__ int sd[256];
  int n = blockIdx.x * 256 + threadIdx.x;
  int deg = 0;
  if (n < NN) deg = cntR[3 * n] + cntR[3 * n + 1] + cntR[3 * n + 2];
  sd[threadIdx.x] = deg;
  __syncthreads();
  #pragma unroll
  for (int s = 128; s > 0; s >>= 1) {
    if (threadIdx.x < s) sd[threadIdx.x] += sd[threadIdx.x + s];
    __syncthreads();
  }
  if (threadIdx.x == 0) bsum[blockIdx.x] = sd[0];
}

__global__ __launch_bounds__(256) void scanB(int* __restrict__ bsum) {
  __shared__ int sd[256];
  int v = (threadIdx.x < NB) ? bsum[threadIdx.x] : 0;
  sd[threadIdx.x] = v;
  __syncthreads();
  for (int s = 1; s < 256; s <<= 1) {
    int t = (threadIdx.x >= s) ? sd[threadIdx.x - s] : 0;
    __syncthreads();
    sd[threadIdx.x] += t;
    __syncthreads();
  }
  if (threadIdx.x < NB) bsum[threadIdx.x] = sd[threadIdx.x] - v;  // exclusive
}

__global__ __launch_bounds__(256) void scanC(
    const int* __restrict__ cntR, const int* __restrict__ bsum,
    int* __restrict__ off, int* __restrict__ cursor, int* __restrict__ degA,
    float* __restrict__ dinv)
{
  __shared__ int sd[256];
  int n = blockIdx.x * 256 + threadIdx.x;
  int c0 = 0, c1 = 0, c2 = 0;
  if (n < NN) { c0 = cntR[3 * n]; c1 = cntR[3 * n + 1]; c2 = cntR[3 * n + 2]; }
  int deg = c0 + c1 + c2;
  sd[threadIdx.x] = deg;
  __syncthreads();
  for (int s = 1; s < 256; s <<= 1) {
    int t = (threadIdx.x >= s) ? sd[threadIdx.x - s] : 0;
    __syncthreads();
    sd[threadIdx.x] += t;
    __syncthreads();
  }
  if (n < NN) {
    int o = bsum[blockIdx.x] + sd[threadIdx.x] - deg;
    off[n] = o; cursor[n] = o; degA[n] = deg;
    dinv[3 * n + 0] = 1.0f / (float)(c0 > 1 ? c0 : 1);
    dinv[3 * n + 1] = 1.0f / (float)(c1 > 1 ? c1 : 1);
    dinv[3 * n + 2] = 1.0f / (float)(c2 > 1 ? c2 : 1);
  }
}

__global__ __launch_bounds__(256) void scatter_kernel(
    const int* __restrict__ ei, const int* __restrict__ et,
    int* __restrict__ cursor, int* __restrict__ sorted)
{
  int e = blockIdx.x * blockDim.x + threadIdx.x;
  if (e >= NE) return;
  int s = ei[e], d = ei[NE + e], r = et[e];
  int pos = atomicAdd(&cursor[d], 1);
  sorted[pos] = (r << 16) | s;
}

// ---------------- layer-0 aggregation from CSR: thread per node, no atomics ----------------
__global__ __launch_bounds__(256) void agg0_csr(
    const float* __restrict__ x, const int* __restrict__ off, const int* __restrict__ degA,
    const int* __restrict__ sorted, float* __restrict__ agg0)
{
  int n = blockIdx.x * blockDim.x + threadIdx.x;
  if (n >= NN) return;
  int start = off[n], deg = degA[n];
  float acc[9];
  #pragma unroll
  for (int i = 0; i < 9; i++) acc[i] = 0.f;
  for (int i = 0; i < deg; i++) {
    int e = sorted[start + i];
    int s = e & 0xFFFF, r = e >> 16;
    acc[r * 3 + 0] += x[s * 3 + 0];
    acc[r * 3 + 1] += x[s * 3 + 1];
    acc[r * 3 + 2] += x[s * 3 + 2];
  }
  #pragma unroll
  for (int i = 0; i < 9; i++) agg0[n * 9 + i] = acc[i];
}

// ---------------- pack W1 (first 256 rows) into MFMA B-fragment order, bf16 ------------------
__global__ __launch_bounds__(256) void pack_w1(const float* __restrict__ W1, unsigned short* __restrict__ pk) {
  for (int idx = threadIdx.x; idx < 8192; idx += 256) {
    int j = idx & 7, l = (idx >> 3) & 63, nt = (idx >> 9) & 1, t = idx >> 10;
    int k = t * 32 + (l >> 4) * 8 + j;
    int n = nt * 16 + (l & 15);
    pk[idx] = f2bf(W1[k * 32 + n]);
  }
}

// ---------------- CSR aggregation: one wave per node, bf16 gather, plain stores --------------
__global__ __launch_bounds__(256) void agg_csr(
    const unsigned short* __restrict__ hb, const int* __restrict__ off, const int* __restrict__ degA,
    const int* __restrict__ sorted, float* __restrict__ agg)
{
  int wid = (blockIdx.x * blockDim.x + threadIdx.x) >> 6;
  int lane = threadIdx.x & 63;
  if (wid >= NN) return;
  int start = off[wid], deg = degA[wid];
  float a0 = 0.f, a1 = 0.f, a2 = 0.f;
  for (int base = 0; base < deg; base += 64) {
    int cnt = deg - base; if (cnt > 64) cnt = 64;
    int ent = (lane < cnt) ? sorted[start + base + lane] : 0;
    for (int j = 0; j < cnt; j++) {
      int e = __shfl(ent, j, 64);
      int s = e & 0xFFFF;
      int r = e >> 16;
      float v = bf2f(hb[s * HD + lane]);
      if (r == 0) a0 += v; else if (r == 1) a1 += v; else a2 += v;
    }
  }
  float* p = agg + wid * 192 + lane;
  p[0] = a0; p[64] = a1; p[128] = a2;
}

// ---------------- layer 0 node update (IN=3) + relu + residual + LN ----------------
__global__ __launch_bounds__(256) void node0_kernel(
    const float* __restrict__ x, const float* __restrict__ agg0, const float* __restrict__ dinv,
    const float* __restrict__ w0, const float* __restrict__ root0, const float* __restrict__ b0,
    const float* __restrict__ res_w, const float* __restrict__ res_b,
    const float* __restrict__ g, const float* __restrict__ bb,
    float* __restrict__ h1, unsigned short* __restrict__ h1b)
{
  int wid = __builtin_amdgcn_readfirstlane((int)((blockIdx.x * blockDim.x + threadIdx.x) >> 6));
  int lane = threadIdx.x & 63;
  int n0 = wid * 8;
  if (n0 >= NN) return;
  float wr[3], ww[9], wres[3];
  #pragma unroll
  for (int i = 0; i < 3; i++) { wr[i] = root0[i * HD + lane]; wres[i] = res_w[i * HD + lane]; }
  #pragma unroll
  for (int i = 0; i < 9; i++) ww[i] = w0[i * HD + lane];
  float vb = b0[lane], vrb = res_b[lane], vg = g[lane], vbb = bb[lane];
  #pragma unroll
  for (int k = 0; k < 8; k++) {
    int nk = n0 + k;
    float xv[3];
    #pragma unroll
    for (int i = 0; i < 3; i++) xv[i] = x[nk * 3 + i];
    float v = vb;
    #pragma unroll
    for (int i = 0; i < 3; i++) v = fmaf(xv[i], wr[i], v);
    #pragma unroll
    for (int r = 0; r < 3; r++) {
      float s = 0.f;
      #pragma unroll
      for (int i = 0; i < 3; i++) s = fmaf(agg0[nk * 9 + r * 3 + i], ww[r * 3 + i], s);
      v = fmaf(dinv[nk * 3 + r], s, v);
    }
    v = fmaxf(v, 0.f);
    float res = vrb;
    #pragma unroll
    for (int i = 0; i < 3; i++) res = fmaf(xv[i], wres[i], res);
    float t = v + res;
    float mu = wave_sum(t) * 0.015625f;
    float dt = t - mu;
    float var = wave_sum(dt * dt) * 0.015625f;
    float o = dt * rsqrtf(var + 1e-5f) * vg + vbb;
    h1[nk * HD + lane] = o;
    h1b[nk * HD + lane] = f2bf(o);
  }
}

// ---------------- H->H node update + relu + residual + LN (fp32 and/or bf16 out) -------------
__global__ __launch_bounds__(256) void node_hh(
    const float* __restrict__ hin, const float* __restrict__ agg, const float* __restrict__ dinv,
    const float* __restrict__ W, const float* __restrict__ root, const float* __restrict__ bias,
    const float* __restrict__ g, const float* __restrict__ bb,
    float* __restrict__ hout, unsigned short* __restrict__ hout_b)
{
  int wid = __builtin_amdgcn_readfirstlane((int)((blockIdx.x * blockDim.x + threadIdx.x) >> 6));
  int lane = threadIdx.x & 63;
  int n0 = wid * 8;
  if (n0 >= NN) return;
  float accR[8], accA0[8], accA1[8], accA2[8];
  #pragma unroll
  for (int k = 0; k < 8; k++) { accR[k] = 0.f; accA0[k] = 0.f; accA1[k] = 0.f; accA2[k] = 0.f; }
  #pragma unroll 4
  for (int i = 0; i < HD; i++) {
    float wr  = root[i * HD + lane];
    float wa0 = W[i * HD + lane];
    float wa1 = W[4096 + i * HD + lane];
    float wa2 = W[8192 + i * HD + lane];
    #pragma unroll
    for (int k = 0; k < 8; k++) {
      int nk = n0 + k;
      accR[k]  = fmaf(hin[nk * HD + i],        wr,  accR[k]);
      accA0[k] = fmaf(agg[nk * 192 + i],       wa0, accA0[k]);
      accA1[k] = fmaf(agg[nk * 192 + 64 + i],  wa1, accA1[k]);
      accA2[k] = fmaf(agg[nk * 192 + 128 + i], wa2, accA2[k]);
    }
  }
  float vb = bias[lane], vg = g[lane], vbb = bb[lane];
  #pragma unroll
  for (int k = 0; k < 8; k++) {
    int nk = n0 + k;
    float v = vb + accR[k];
    v = fmaf(dinv[nk * 3 + 0], accA0[k], v);
    v = fmaf(dinv[nk * 3 + 1], accA1[k], v);
    v = fmaf(dinv[nk * 3 + 2], accA2[k], v);
    v = fmaxf(v, 0.f);
    float t = v + hin[nk * HD + lane];
    float mu = wave_sum(t) * 0.015625f;
    float dt = t - mu;
    float var = wave_sum(dt * dt) * 0.015625f;
    float o = dt * rsqrtf(var + 1e-5f) * vg + vbb;
    if (hout)   hout[nk * HD + lane] = o;
    if (hout_b) hout_b[nk * HD + lane] = f2bf(o);
  }
}

// ---------------- decoder: 16 edges/wave, bf16 MFMA for the 262x32 layer ----------------
__global__ __launch_bounds__(256) void decoder_mfma(
    const unsigned short* __restrict__ h3b, const int* __restrict__ ei, const float* __restrict__ ea,
    const unsigned short* __restrict__ pk, const float* __restrict__ W1f, const float* __restrict__ B1,
    const float* __restrict__ W2, const float* __restrict__ B2,
    const float* __restrict__ W3, const float* __restrict__ B3,
    float* __restrict__ out)
{
  __shared__ float lds[4 * 16 * 33];
  int wv = threadIdx.x >> 6;
  int lane = threadIdx.x & 63;
  int e0 = (blockIdx.x * 4 + wv) * 16;
  int m = lane & 15, g = lane >> 4;

  int s = ei[e0 + m], d = ei[NE + e0 + m];
  short8 hs0 = *(const short8*)(h3b + (size_t)s * HD + g * 8);
  short8 hs1 = *(const short8*)(h3b + (size_t)s * HD + 32 + g * 8);
  short8 hd0 = *(const short8*)(h3b + (size_t)d * HD + g * 8);
  short8 hd1 = *(const short8*)(h3b + (size_t)d * HD + 32 + g * 8);

  short8 ad0, ad1, pd0, pd1;
  #pragma unroll
  for (int j = 0; j < 8; j++) {
    float a0 = bf2f((unsigned short)hs0[j]), b0 = bf2f((unsigned short)hd0[j]);
    float a1 = bf2f((unsigned short)hs1[j]), b1 = bf2f((unsigned short)hd1[j]);
    ad0[j] = (short)f2bf(fabsf(a0 - b0));
    ad1[j] = (short)f2bf(fabsf(a1 - b1));
    pd0[j] = (short)f2bf(a0 * b0);
    pd1[j] = (short)f2bf(a1 * b1);
  }

  short8 A[8] = {hs0, hs1, hd0, hd1, ad0, ad1, pd0, pd1};
  const short8* pkv = (const short8*)pk;
  f32x4 acc0 = {0.f, 0.f, 0.f, 0.f};
  f32x4 acc1 = {0.f, 0.f, 0.f, 0.f};
  #pragma unroll
  for (int t = 0; t < 8; t++) {
    acc0 = __builtin_amdgcn_mfma_f32_16x16x32_bf16(A[t], pkv[(t * 2 + 0) * 64 + lane], acc0, 0, 0, 0);
    acc1 = __builtin_amdgcn_mfma_f32_16x16x32_bf16(A[t], pkv[(t * 2 + 1) * 64 + lane], acc1, 0, 0, 0);
  }

  // epilogue phase 1: bias + edge_attr tail (fp32) + relu -> LDS (stride 33)
  int cn = lane & 15;  // output column
  float wt0[6], wt1[6];
  #pragma unroll
  for (int k = 0; k < 6; k++) {
    wt0[k] = W1f[(256 + k) * 32 + cn];
    wt1[k] = W1f[(256 + k) * 32 + 16 + cn];
  }
  float b1a = B1[cn], b1b = B1[16 + cn];
  float* Z = lds + wv * 528;
  #pragma unroll
  for (int r = 0; r < 4; r++) {
    int mr = g * 4 + r;
    float z0 = acc0[r] + b1a;
    float z1 = acc1[r] + b1b;
    #pragma unroll
    for (int k = 0; k < 6; k++) {
      float eav = ea[(size_t)(e0 + mr) * 6 + k];
      z0 = fmaf(eav, wt0[k], z0);
      z1 = fmaf(eav, wt1[k], z1);
    }
    Z[mr * 33 + cn] = fmaxf(z0, 0.f);
    Z[mr * 33 + 16 + cn] = fmaxf(z1, 0.f);
  }

  // epilogue phase 2: z2 (16) in 4 lanes/edge, then z3 + shuffle reduce
  int me = lane & 15, q = g;
  float z2[4];
  #pragma unroll
  for (int p = 0; p < 4; p++) z2[p] = B2[q * 4 + p];
  #pragma unroll 8
  for (int n = 0; n < 32; n++) {
    float zv = Z[me * 33 + n];
    const float4 w2v = *(const float4*)(W2 + n * 16 + q * 4);
    z2[0] = fmaf(zv, w2v.x, z2[0]);
    z2[1] = fmaf(zv, w2v.y, z2[1]);
    z2[2] = fmaf(zv, w2v.z, z2[2]);
    z2[3] = fmaf(zv, w2v.w, z2[3]);
  }
  const float4 w3v = *(const float4*)(W3 + q * 4);
  float part = fmaxf(z2[0], 0.f) * w3v.x + fmaxf(z2[1], 0.f) * w3v.y +
               fmaxf(z2[2], 0.f) * w3v.z + fmaxf(z2[3], 0.f) * w3v.w;
  part += __shfl_xor(part, 16, 64);
  part += __shfl_xor(part, 32, 64);
  if (g == 0) out[e0 + me] = part + B3[0];
}

extern "C" void kernel_launch(void* const* d_in, const int* in_sizes, int n_in,
                              void* d_out, int out_size, void* d_ws, size_t ws_size,
                              hipStream_t stream) {
  const float* x      = (const float*)d_in[0];
  const int*   ei     = (const int*)d_in[1];
  const float* ea     = (const float*)d_in[2];
  const float* w0     = (const float*)d_in[3];
  const float* root0  = (const float*)d_in[4];
  const float* b0     = (const float*)d_in[5];
  const float* w1     = (const float*)d_in[6];
  const float* root1  = (const float*)d_in[7];
  const float* b1     = (const float*)d_in[8];
  const float* w2     = (const float*)d_in[9];
  const float* root2  = (const float*)d_in[10];
  const float* b2     = (const float*)d_in[11];
  const float* ln_g0  = (const float*)d_in[12];
  const float* ln_b0  = (const float*)d_in[13];
  const float* ln_g1  = (const float*)d_in[14];
  const float* ln_b1  = (const float*)d_in[15];
  const float* ln_g2  = (const float*)d_in[16];
  const float* ln_b2  = (const float*)d_in[17];
  const float* res_w  = (const float*)d_in[18];
  const float* res_b  = (const float*)d_in[19];
  const float* dec_w1 = (const float*)d_in[20];
  const float* dec_b1 = (const float*)d_in[21];
  const float* dec_w2 = (const float*)d_in[22];
  const float* dec_b2 = (const float*)d_in[23];
  const float* dec_w3 = (const float*)d_in[24];
  const float* dec_b3 = (const float*)d_in[25];

  char* ws = (char*)d_ws;
  int*   et     = (int*)(ws + 0);             //  3,200,000 B
  int*   cntR   = (int*)(ws + 3200000);       //    600,000 B  (memset 0)
  float* agg0   = (float*)(ws + 3800000);     //  1,800,000 B  (fully overwritten)
  int*   bsum   = (int*)(ws + 5600000);       //      1,024 B
  int*   off    = (int*)(ws + 5601024);       //    200,000 B
  int*   cursor = (int*)(ws + 5801024);       //    200,000 B
  int*   degA   = (int*)(ws + 6001024);       //    200,000 B
  float* dinv   = (float*)(ws + 6201024);     //    600,000 B
  int*   sorted = (int*)(ws + 6801024);       //  3,200,000 B
  float* agg    = (float*)(ws + 10001024);    // 38,400,000 B
  float* h1     = (float*)(ws + 48401024);    // 12,800,000 B
  float* h2     = (float*)(ws + 61201024);    // 12,800,000 B
  // one 6.4 MB bf16 buffer, serially reused: h1b -> h2b -> h3b (lifetimes disjoint)
  unsigned short* hb  = (unsigned short*)(ws + 74001024);  // 6,400,000 B
  unsigned short* pkw = (unsigned short*)(ws + 80401024);  //    16,384 B (end 80,417,408)

  hipMemsetAsync(cntR, 0, 600000, stream);

  edge_prep<<<(NE + 255) / 256, 256, 0, stream>>>(ei, ea, et, cntR);
  scanA<<<NB, 256, 0, stream>>>(cntR, bsum);
  scanB<<<1, 256, 0, stream>>>(bsum);
  scanC<<<NB, 256, 0, stream>>>(cntR, bsum, off, cursor, degA, dinv);
  scatter_kernel<<<(NE + 255) / 256, 256, 0, stream>>>(ei, et, cursor, sorted);
  pack_w1<<<1, 256, 0, stream>>>(dec_w1, pkw);
  agg0_csr<<<NB, 256, 0, stream>>>(x, off, degA, sorted, agg0);

  const int node_blocks = (NN / 8 + 3) / 4;   // 8 nodes/wave, 4 waves/block
  const int agg_blocks  = (NN + 3) / 4;       // 1 node/wave, 4 waves/block

  node0_kernel<<<node_blocks, 256, 0, stream>>>(x, agg0, dinv, w0, root0, b0,
                                                res_w, res_b, ln_g0, ln_b0, h1, hb);

  agg_csr<<<agg_blocks, 256, 0, stream>>>(hb, off, degA, sorted, agg);
  node_hh<<<node_blocks, 256, 0, stream>>>(h1, agg, dinv, w1, root1, b1, ln_g1, ln_b1, h2, hb);

  agg_csr<<<agg_blocks, 256, 0, stream>>>(hb, off, degA, sorted, agg);
  node_hh<<<node_blocks, 256, 0, stream>>>(h2, agg, dinv, w2, root2, b2, ln_g2, ln_b2, nullptr, hb);

  decoder_mfma<<<NE / 64, 256, 0, stream>>>(hb, ei, ea, pkw, dec_w1, dec_b1,
                                            dec_w2, dec_b2, dec_w3, dec_b3, (float*)d_out);
}

// Round 5
// 606.437 us; speedup vs baseline: 3.5636x; 1.0725x over previous
//
#include <hip/hip_runtime.h>
#include <math.h>

#define NN 50000
#define NE 800000
#define HD 64
#define NB 196  // ceil(50000/256)

typedef float f32x4 __attribute__((ext_vector_type(4)));
typedef short short8 __attribute__((ext_vector_type(8)));

__device__ __forceinline__ float wave_sum(float v) {
  #pragma unroll
  for (int off = 32; off > 0; off >>= 1) v += __shfl_xor(v, off, 64);
  return v;
}

__device__ __forceinline__ unsigned short f2bf(float f) {
  union { float f; unsigned u; } v; v.f = f;
  unsigned r = v.u + 0x7FFF + ((v.u >> 16) & 1);  // RNE
  return (unsigned short)(r >> 16);
}
__device__ __forceinline__ float bf2f(unsigned short b) {
  union { unsigned u; float f; } v; v.u = ((unsigned)b) << 16;
  return v.f;
}

// ---------------- edge prep: edge_type + per-(dst,rel) histogram ----------------
__global__ __launch_bounds__(256) void edge_prep(
    const int* __restrict__ ei, const float* __restrict__ ea,
    int* __restrict__ et, int* __restrict__ cntR)
{
  int e = blockIdx.x * blockDim.x + threadIdx.x;
  if (e >= NE) return;
  float dist = ea[e * 6];
  const float q1 = log1pf(5000.0f);
  const float q2 = log1pf(10000.0f);
  int r = (dist > q1 ? 1 : 0) + (dist > q2 ? 1 : 0);
  et[e] = r;
  int d = ei[NE + e];
  atomicAdd(&cntR[d * 3 + r], 1);
}

// ---------------- CSR build (relation-sorted: runs r=0,1,2 per node) ----------------
__global__ __launch_bounds__(256) void scanA(const int* __restrict__ cntR, int* __restrict__ bsum) {
  __shared__ int sd[256];
  int n = blockIdx.x * 256 + threadIdx.x;
  int deg = 0;
  if (n < NN) deg = cntR[3 * n] + cntR[3 * n + 1] + cntR[3 * n + 2];
  sd[threadIdx.x] = deg;
  __syncthreads();
  #pragma unroll
  for (int s = 128; s > 0; s >>= 1) {
    if (threadIdx.x < s) sd[threadIdx.x] += sd[threadIdx.x + s];
    __syncthreads();
  }
  if (threadIdx.x == 0) bsum[blockIdx.x] = sd[0];
}

__global__ __launch_bounds__(256) void scanB(int* __restrict__ bsum) {
  __shared__ int sd[256];
  int v = (threadIdx.x < NB) ? bsum[threadIdx.x] : 0;
  sd[threadIdx.x] = v;
  __syncthreads();
  for (int s = 1; s < 256; s <<= 1) {
    int t = (threadIdx.x >= s) ? sd[threadIdx.x - s] : 0;
    __syncthreads();
    sd[threadIdx.x] += t;
    __syncthreads();
  }
  if (threadIdx.x < NB) bsum[threadIdx.x] = sd[threadIdx.x] - v;  // exclusive
}

__global__ __launch_bounds__(256) void scanC(
    const int* __restrict__ cntR, const int* __restrict__ bsum,
    int* __restrict__ off3, int* __restrict__ cursor3, float* __restrict__ dinv)
{
  __shared__ int sd[256];
  int n = blockIdx.x * 256 + threadIdx.x;
  int c0 = 0, c1 = 0, c2 = 0;
  if (n < NN) { c0 = cntR[3 * n]; c1 = cntR[3 * n + 1]; c2 = cntR[3 * n + 2]; }
  int deg = c0 + c1 + c2;
  sd[threadIdx.x] = deg;
  __syncthreads();
  for (int s = 1; s < 256; s <<= 1) {
    int t = (threadIdx.x >= s) ? sd[threadIdx.x - s] : 0;
    __syncthreads();
    sd[threadIdx.x] += t;
    __syncthreads();
  }
  if (n < NN) {
    int o = bsum[blockIdx.x] + sd[threadIdx.x] - deg;
    off3[3 * n + 0] = o;           cursor3[3 * n + 0] = o;
    off3[3 * n + 1] = o + c0;      cursor3[3 * n + 1] = o + c0;
    off3[3 * n + 2] = o + c0 + c1; cursor3[3 * n + 2] = o + c0 + c1;
    dinv[3 * n + 0] = 1.0f / (float)(c0 > 1 ? c0 : 1);
    dinv[3 * n + 1] = 1.0f / (float)(c1 > 1 ? c1 : 1);
    dinv[3 * n + 2] = 1.0f / (float)(c2 > 1 ? c2 : 1);
  }
}

__global__ __launch_bounds__(256) void scatter_kernel(
    const int* __restrict__ ei, const int* __restrict__ et,
    int* __restrict__ cursor3, int* __restrict__ sorted)
{
  int e = blockIdx.x * blockDim.x + threadIdx.x;
  if (e >= NE) return;
  int s = ei[e], d = ei[NE + e], r = et[e];
  int pos = atomicAdd(&cursor3[d * 3 + r], 1);
  sorted[pos] = s;  // src only; relation implied by run
}

// ---------------- layer-0 aggregation from CSR: thread per node, run-wise ----------------
__global__ __launch_bounds__(256) void agg0_csr(
    const float* __restrict__ x, const int* __restrict__ off3, const int* __restrict__ cntR,
    const int* __restrict__ sorted, float* __restrict__ agg0)
{
  int n = blockIdx.x * blockDim.x + threadIdx.x;
  if (n >= NN) return;
  #pragma unroll
  for (int r = 0; r < 3; r++) {
    int st = off3[3 * n + r], len = cntR[3 * n + r];
    float ax = 0.f, ay = 0.f, az = 0.f;
    for (int i = 0; i < len; i++) {
      int s = sorted[st + i];
      ax += x[s * 3 + 0];
      ay += x[s * 3 + 1];
      az += x[s * 3 + 2];
    }
    agg0[n * 9 + r * 3 + 0] = ax;
    agg0[n * 9 + r * 3 + 1] = ay;
    agg0[n * 9 + r * 3 + 2] = az;
  }
}

// ---------------- pack W1 (256 rows) and W2 (32x16) into MFMA B-fragment order, bf16 ---------
__global__ __launch_bounds__(256) void pack_w(
    const float* __restrict__ W1, const float* __restrict__ W2,
    unsigned short* __restrict__ pk, unsigned short* __restrict__ pk2)
{
  for (int idx = threadIdx.x; idx < 8192; idx += 256) {
    int j = idx & 7, l = (idx >> 3) & 63, nt = (idx >> 9) & 1, t = idx >> 10;
    int k = t * 32 + (l >> 4) * 8 + j;
    int n = nt * 16 + (l & 15);
    pk[idx] = f2bf(W1[k * 32 + n]);
  }
  for (int idx = threadIdx.x; idx < 512; idx += 256) {
    int j = idx & 7, l = idx >> 3;         // l = lane
    int k = (l >> 4) * 8 + j, n = l & 15;  // B[k][n]
    pk2[idx] = f2bf(W2[k * 16 + n]);
  }
}

// ---------------- CSR aggregation: one wave per node, bf16 gather, run-wise ----------------
__global__ __launch_bounds__(256) void agg_csr(
    const unsigned short* __restrict__ hb, const int* __restrict__ off3, const int* __restrict__ cntR,
    const int* __restrict__ sorted, float* __restrict__ agg)
{
  int wid = (blockIdx.x * blockDim.x + threadIdx.x) >> 6;
  int lane = threadIdx.x & 63;
  if (wid >= NN) return;
  float* p = agg + wid * 192 + lane;
  #pragma unroll
  for (int r = 0; r < 3; r++) {
    int st = off3[wid * 3 + r], len = cntR[wid * 3 + r];
    float a = 0.f;
    for (int base = 0; base < len; base += 64) {
      int cnt = len - base; if (cnt > 64) cnt = 64;
      int ent = (lane < cnt) ? sorted[st + base + lane] : 0;
      for (int j = 0; j < cnt; j++) {
        int s = __shfl(ent, j, 64);
        a += bf2f(hb[s * HD + lane]);
      }
    }
    p[r * 64] = a;
  }
}

// ---------------- layer 0 node update (IN=3) + relu + residual + LN ----------------
__global__ __launch_bounds__(256) void node0_kernel(
    const float* __restrict__ x, const float* __restrict__ agg0, const float* __restrict__ dinv,
    const float* __restrict__ w0, const float* __restrict__ root0, const float* __restrict__ b0,
    const float* __restrict__ res_w, const float* __restrict__ res_b,
    const float* __restrict__ g, const float* __restrict__ bb,
    float* __restrict__ h1, unsigned short* __restrict__ h1b)
{
  int wid = __builtin_amdgcn_readfirstlane((int)((blockIdx.x * blockDim.x + threadIdx.x) >> 6));
  int lane = threadIdx.x & 63;
  int n0 = wid * 8;
  if (n0 >= NN) return;
  float wr[3], ww[9], wres[3];
  #pragma unroll
  for (int i = 0; i < 3; i++) { wr[i] = root0[i * HD + lane]; wres[i] = res_w[i * HD + lane]; }
  #pragma unroll
  for (int i = 0; i < 9; i++) ww[i] = w0[i * HD + lane];
  float vb = b0[lane], vrb = res_b[lane], vg = g[lane], vbb = bb[lane];
  #pragma unroll
  for (int k = 0; k < 8; k++) {
    int nk = n0 + k;
    float xv[3];
    #pragma unroll
    for (int i = 0; i < 3; i++) xv[i] = x[nk * 3 + i];
    float v = vb;
    #pragma unroll
    for (int i = 0; i < 3; i++) v = fmaf(xv[i], wr[i], v);
    #pragma unroll
    for (int r = 0; r < 3; r++) {
      float s = 0.f;
      #pragma unroll
      for (int i = 0; i < 3; i++) s = fmaf(agg0[nk * 9 + r * 3 + i], ww[r * 3 + i], s);
      v = fmaf(dinv[nk * 3 + r], s, v);
    }
    v = fmaxf(v, 0.f);
    float res = vrb;
    #pragma unroll
    for (int i = 0; i < 3; i++) res = fmaf(xv[i], wres[i], res);
    float t = v + res;
    float mu = wave_sum(t) * 0.015625f;
    float dt = t - mu;
    float var = wave_sum(dt * dt) * 0.015625f;
    float o = dt * rsqrtf(var + 1e-5f) * vg + vbb;
    h1[nk * HD + lane] = o;
    h1b[nk * HD + lane] = f2bf(o);
  }
}

// ---------------- H->H node update + relu + residual + LN (fp32 and/or bf16 out) -------------
__global__ __launch_bounds__(256) void node_hh(
    const float* __restrict__ hin, const float* __restrict__ agg, const float* __restrict__ dinv,
    const float* __restrict__ W, const float* __restrict__ root, const float* __restrict__ bias,
    const float* __restrict__ g, const float* __restrict__ bb,
    float* __restrict__ hout, unsigned short* __restrict__ hout_b)
{
  int wid = __builtin_amdgcn_readfirstlane((int)((blockIdx.x * blockDim.x + threadIdx.x) >> 6));
  int lane = threadIdx.x & 63;
  int n0 = wid * 8;
  if (n0 >= NN) return;
  float accR[8], accA0[8], accA1[8], accA2[8];
  #pragma unroll
  for (int k = 0; k < 8; k++) { accR[k] = 0.f; accA0[k] = 0.f; accA1[k] = 0.f; accA2[k] = 0.f; }
  #pragma unroll 4
  for (int i = 0; i < HD; i++) {
    float wr  = root[i * HD + lane];
    float wa0 = W[i * HD + lane];
    float wa1 = W[4096 + i * HD + lane];
    float wa2 = W[8192 + i * HD + lane];
    #pragma unroll
    for (int k = 0; k < 8; k++) {
      int nk = n0 + k;
      accR[k]  = fmaf(hin[nk * HD + i],        wr,  accR[k]);
      accA0[k] = fmaf(agg[nk * 192 + i],       wa0, accA0[k]);
      accA1[k] = fmaf(agg[nk * 192 + 64 + i],  wa1, accA1[k]);
      accA2[k] = fmaf(agg[nk * 192 + 128 + i], wa2, accA2[k]);
    }
  }
  float vb = bias[lane], vg = g[lane], vbb = bb[lane];
  #pragma unroll
  for (int k = 0; k < 8; k++) {
    int nk = n0 + k;
    float v = vb + accR[k];
    v = fmaf(dinv[nk * 3 + 0], accA0[k], v);
    v = fmaf(dinv[nk * 3 + 1], accA1[k], v);
    v = fmaf(dinv[nk * 3 + 2], accA2[k], v);
    v = fmaxf(v, 0.f);
    float t = v + hin[nk * HD + lane];
    float mu = wave_sum(t) * 0.015625f;
    float dt = t - mu;
    float var = wave_sum(dt * dt) * 0.015625f;
    float o = dt * rsqrtf(var + 1e-5f) * vg + vbb;
    if (hout)   hout[nk * HD + lane] = o;
    if (hout_b) hout_b[nk * HD + lane] = f2bf(o);
  }
}

// ---------------- decoder: 16 edges/wave, MFMA for all three layers ----------------
__global__ __launch_bounds__(256) void decoder_mfma(
    const unsigned short* __restrict__ h3b, const int* __restrict__ ei, const float* __restrict__ ea,
    const unsigned short* __restrict__ pk, const unsigned short* __restrict__ pk2,
    const float* __restrict__ W1f, const float* __restrict__ B1,
    const float* __restrict__ B2, const float* __restrict__ W3, const float* __restrict__ B3,
    float* __restrict__ out)
{
  __shared__ float lds[4 * 32 * 19];   // per wave: Zt[32][19] transposed z, stride 19
  int wv = threadIdx.x >> 6;
  int lane = threadIdx.x & 63;
  int e0 = (blockIdx.x * 4 + wv) * 16;
  int m = lane & 15, g = lane >> 4;

  int s = ei[e0 + m], d = ei[NE + e0 + m];
  short8 hs0 = *(const short8*)(h3b + (size_t)s * HD + g * 8);
  short8 hs1 = *(const short8*)(h3b + (size_t)s * HD + 32 + g * 8);
  short8 hd0 = *(const short8*)(h3b + (size_t)d * HD + g * 8);
  short8 hd1 = *(const short8*)(h3b + (size_t)d * HD + 32 + g * 8);

  short8 ad0, ad1, pd0, pd1;
  #pragma unroll
  for (int j = 0; j < 8; j++) {
    float a0 = bf2f((unsigned short)hs0[j]), b0 = bf2f((unsigned short)hd0[j]);
    float a1 = bf2f((unsigned short)hs1[j]), b1 = bf2f((unsigned short)hd1[j]);
    ad0[j] = (short)f2bf(fabsf(a0 - b0));
    ad1[j] = (short)f2bf(fabsf(a1 - b1));
    pd0[j] = (short)f2bf(a0 * b0);
    pd1[j] = (short)f2bf(a1 * b1);
  }

  short8 A[8] = {hs0, hs1, hd0, hd1, ad0, ad1, pd0, pd1};
  const short8* pkv = (const short8*)pk;
  f32x4 acc0 = {0.f, 0.f, 0.f, 0.f};
  f32x4 acc1 = {0.f, 0.f, 0.f, 0.f};
  #pragma unroll
  for (int t = 0; t < 8; t++) {
    acc0 = __builtin_amdgcn_mfma_f32_16x16x32_bf16(A[t], pkv[(t * 2 + 0) * 64 + lane], acc0, 0, 0, 0);
    acc1 = __builtin_amdgcn_mfma_f32_16x16x32_bf16(A[t], pkv[(t * 2 + 1) * 64 + lane], acc1, 0, 0, 0);
  }

  // phase 1: bias + edge_attr tail (fp32) + relu -> LDS transposed: Zt[n][m] = relu(z[m][n])
  int cn = lane & 15;  // output column within acc0 (n=cn) / acc1 (n=16+cn)
  float wt0[6], wt1[6];
  #pragma unroll
  for (int k = 0; k < 6; k++) {
    wt0[k] = W1f[(256 + k) * 32 + cn];
    wt1[k] = W1f[(256 + k) * 32 + 16 + cn];
  }
  float b1a = B1[cn], b1b = B1[16 + cn];
  float* Z = lds + wv * 608;
  #pragma unroll
  for (int r = 0; r < 4; r++) {
    int mr = g * 4 + r;   // edge row for both accs
    float z0 = acc0[r] + b1a;
    float z1 = acc1[r] + b1b;
    #pragma unroll
    for (int k = 0; k < 6; k++) {
      float eav = ea[(size_t)(e0 + mr) * 6 + k];
      z0 = fmaf(eav, wt0[k], z0);
      z1 = fmaf(eav, wt1[k], z1);
    }
    Z[cn * 19 + mr]        = fmaxf(z0, 0.f);
    Z[(16 + cn) * 19 + mr] = fmaxf(z1, 0.f);
  }
  // wave-private LDS: compiler inserts lgkmcnt waits; no barrier needed

  // phase 2: layer-2 GEMM (16 edges x 16 units, K=32) via one MFMA + layer-3 reduce
  short8 A2;
  #pragma unroll
  for (int j = 0; j < 8; j++)
    A2[j] = (short)f2bf(Z[(g * 8 + j) * 19 + m]);   // A[m=lane&15][k=quad*8+j]
  f32x4 acc2 = {0.f, 0.f, 0.f, 0.f};
  acc2 = __builtin_amdgcn_mfma_f32_16x16x32_bf16(A2, ((const short8*)pk2)[lane], acc2, 0, 0, 0);

  float bias2 = B2[m];   // output col n = lane&15
  float w3v = W3[m];
  float t0 = fmaxf(acc2[0] + bias2, 0.f) * w3v;
  float t1 = fmaxf(acc2[1] + bias2, 0.f) * w3v;
  float t2 = fmaxf(acc2[2] + bias2, 0.f) * w3v;
  float t3 = fmaxf(acc2[3] + bias2, 0.f) * w3v;
  #pragma unroll
  for (int off = 1; off < 16; off <<= 1) {
    t0 += __shfl_xor(t0, off, 64);
    t1 += __shfl_xor(t1, off, 64);
    t2 += __shfl_xor(t2, off, 64);
    t3 += __shfl_xor(t3, off, 64);
  }
  if (m < 4) {
    float val = (m == 0) ? t0 : (m == 1) ? t1 : (m == 2) ? t2 : t3;
    out[e0 + g * 4 + m] = val + B3[0];   // edge = row = quad*4 + reg
  }
}

extern "C" void kernel_launch(void* const* d_in, const int* in_sizes, int n_in,
                              void* d_out, int out_size, void* d_ws, size_t ws_size,
                              hipStream_t stream) {
  const float* x      = (const float*)d_in[0];
  const int*   ei     = (const int*)d_in[1];
  const float* ea     = (const float*)d_in[2];
  const float* w0     = (const float*)d_in[3];
  const float* root0  = (const float*)d_in[4];
  const float* b0     = (const float*)d_in[5];
  const float* w1     = (const float*)d_in[6];
  const float* root1  = (const float*)d_in[7];
  const float* b1     = (const float*)d_in[8];
  const float* w2     = (const float*)d_in[9];
  const float* root2  = (const float*)d_in[10];
  const float* b2     = (const float*)d_in[11];
  const float* ln_g0  = (const float*)d_in[12];
  const float* ln_b0  = (const float*)d_in[13];
  const float* ln_g1  = (const float*)d_in[14];
  const float* ln_b1  = (const float*)d_in[15];
  const float* ln_g2  = (const float*)d_in[16];
  const float* ln_b2  = (const float*)d_in[17];
  const float* res_w  = (const float*)d_in[18];
  const float* res_b  = (const float*)d_in[19];
  const float* dec_w1 = (const float*)d_in[20];
  const float* dec_b1 = (const float*)d_in[21];
  const float* dec_w2 = (const float*)d_in[22];
  const float* dec_b2 = (const float*)d_in[23];
  const float* dec_w3 = (const float*)d_in[24];
  const float* dec_b3 = (const float*)d_in[25];

  char* ws = (char*)d_ws;
  int*   et      = (int*)(ws + 0);             //  3,200,000 B
  int*   cntR    = (int*)(ws + 3200000);       //    600,000 B  (memset 0)
  float* agg0    = (float*)(ws + 3800000);     //  1,800,000 B  (fully overwritten)
  int*   bsum    = (int*)(ws + 5600000);       //      1,024 B
  int*   off3    = (int*)(ws + 5601024);       //    600,000 B
  int*   cursor3 = (int*)(ws + 6201024);       //    600,000 B
  float* dinv    = (float*)(ws + 6801024);     //    600,000 B
  int*   sorted  = (int*)(ws + 7401024);       //  3,200,000 B
  float* agg     = (float*)(ws + 10601024);    // 38,400,000 B
  float* h1      = (float*)(ws + 49001024);    // 12,800,000 B
  float* h2      = (float*)(ws + 61801024);    // 12,800,000 B
  unsigned short* hb   = (unsigned short*)(ws + 74601024);  // 6,400,000 B (h1b->h2b->h3b)
  unsigned short* pkw  = (unsigned short*)(ws + 81001024);  //    16,384 B
  unsigned short* pkw2 = (unsigned short*)(ws + 81017408);  //     1,024 B (end 81,018,432)

  hipMemsetAsync(cntR, 0, 600000, stream);

  edge_prep<<<(NE + 255) / 256, 256, 0, stream>>>(ei, ea, et, cntR);
  scanA<<<NB, 256, 0, stream>>>(cntR, bsum);
  scanB<<<1, 256, 0, stream>>>(bsum);
  scanC<<<NB, 256, 0, stream>>>(cntR, bsum, off3, cursor3, dinv);
  scatter_kernel<<<(NE + 255) / 256, 256, 0, stream>>>(ei, et, cursor3, sorted);
  pack_w<<<1, 256, 0, stream>>>(dec_w1, dec_w2, pkw, pkw2);
  agg0_csr<<<NB, 256, 0, stream>>>(x, off3, cntR, sorted, agg0);

  const int node_blocks = (NN / 8 + 3) / 4;   // 8 nodes/wave, 4 waves/block
  const int agg_blocks  = (NN + 3) / 4;       // 1 node/wave, 4 waves/block

  node0_kernel<<<node_blocks, 256, 0, stream>>>(x, agg0, dinv, w0, root0, b0,
                                                res_w, res_b, ln_g0, ln_b0, h1, hb);

  agg_csr<<<agg_blocks, 256, 0, stream>>>(hb, off3, cntR, sorted, agg);
  node_hh<<<node_blocks, 256, 0, stream>>>(h1, agg, dinv, w1, root1, b1, ln_g1, ln_b1, h2, hb);

  agg_csr<<<agg_blocks, 256, 0, stream>>>(hb, off3, cntR, sorted, agg);
  node_hh<<<node_blocks, 256, 0, stream>>>(h2, agg, dinv, w2, root2, b2, ln_g2, ln_b2, nullptr, hb);

  decoder_mfma<<<NE / 64, 256, 0, stream>>>(hb, ei, ea, pkw, pkw2, dec_w1, dec_b1,
                                            dec_b2, dec_w3, dec_b3, (float*)d_out);
}

// Round 6
// 478.166 us; speedup vs baseline: 4.5196x; 1.2683x over previous
//
#include <hip/hip_runtime.h>
#include <math.h>

#define NN 50000
#define NE 800000
#define HD 64
#define NB 196  // ceil(50000/256)

typedef float f32x4 __attribute__((ext_vector_type(4)));
typedef short short8 __attribute__((ext_vector_type(8)));

__device__ __forceinline__ float wave_sum(float v) {
  #pragma unroll
  for (int off = 32; off > 0; off >>= 1) v += __shfl_xor(v, off, 64);
  return v;
}

__device__ __forceinline__ unsigned short f2bf(float f) {
  union { float f; unsigned u; } v; v.f = f;
  unsigned r = v.u + 0x7FFF + ((v.u >> 16) & 1);  // RNE
  return (unsigned short)(r >> 16);
}
__device__ __forceinline__ float bf2f(unsigned short b) {
  union { unsigned u; float f; } v; v.u = ((unsigned)b) << 16;
  return v.f;
}

// ---------------- edge prep: edge_type + per-(dst,rel) histogram ----------------
__global__ __launch_bounds__(256) void edge_prep(
    const int* __restrict__ ei, const float* __restrict__ ea,
    int* __restrict__ et, int* __restrict__ cntR)
{
  int e = blockIdx.x * blockDim.x + threadIdx.x;
  if (e >= NE) return;
  float dist = ea[e * 6];
  const float q1 = log1pf(5000.0f);
  const float q2 = log1pf(10000.0f);
  int r = (dist > q1 ? 1 : 0) + (dist > q2 ? 1 : 0);
  et[e] = r;
  int d = ei[NE + e];
  atomicAdd(&cntR[d * 3 + r], 1);
}

// ---------------- CSR build (relation-sorted: runs r=0,1,2 per node) ----------------
__global__ __launch_bounds__(256) void scanA(const int* __restrict__ cntR, int* __restrict__ bsum) {
  __shared__ int sd[256];
  int n = blockIdx.x * 256 + threadIdx.x;
  int deg = 0;
  if (n < NN) deg = cntR[3 * n] + cntR[3 * n + 1] + cntR[3 * n + 2];
  sd[threadIdx.x] = deg;
  __syncthreads();
  #pragma unroll
  for (int s = 128; s > 0; s >>= 1) {
    if (threadIdx.x < s) sd[threadIdx.x] += sd[threadIdx.x + s];
    __syncthreads();
  }
  if (threadIdx.x == 0) bsum[blockIdx.x] = sd[0];
}

__global__ __launch_bounds__(256) void scanB(int* __restrict__ bsum) {
  __shared__ int sd[256];
  int v = (threadIdx.x < NB) ? bsum[threadIdx.x] : 0;
  sd[threadIdx.x] = v;
  __syncthreads();
  for (int s = 1; s < 256; s <<= 1) {
    int t = (threadIdx.x >= s) ? sd[threadIdx.x - s] : 0;
    __syncthreads();
    sd[threadIdx.x] += t;
    __syncthreads();
  }
  if (threadIdx.x < NB) bsum[threadIdx.x] = sd[threadIdx.x] - v;  // exclusive
}

__global__ __launch_bounds__(256) void scanC(
    const int* __restrict__ cntR, const int* __restrict__ bsum,
    int* __restrict__ off3, int* __restrict__ cursor3, float* __restrict__ dinv)
{
  __shared__ int sd[256];
  int n = blockIdx.x * 256 + threadIdx.x;
  int c0 = 0, c1 = 0, c2 = 0;
  if (n < NN) { c0 = cntR[3 * n]; c1 = cntR[3 * n + 1]; c2 = cntR[3 * n + 2]; }
  int deg = c0 + c1 + c2;
  sd[threadIdx.x] = deg;
  __syncthreads();
  for (int s = 1; s < 256; s <<= 1) {
    int t = (threadIdx.x >= s) ? sd[threadIdx.x - s] : 0;
    __syncthreads();
    sd[threadIdx.x] += t;
    __syncthreads();
  }
  if (n < NN) {
    int o = bsum[blockIdx.x] + sd[threadIdx.x] - deg;
    off3[3 * n + 0] = o;           cursor3[3 * n + 0] = o;
    off3[3 * n + 1] = o + c0;      cursor3[3 * n + 1] = o + c0;
    off3[3 * n + 2] = o + c0 + c1; cursor3[3 * n + 2] = o + c0 + c1;
    dinv[3 * n + 0] = 1.0f / (float)(c0 > 1 ? c0 : 1);
    dinv[3 * n + 1] = 1.0f / (float)(c1 > 1 ? c1 : 1);
    dinv[3 * n + 2] = 1.0f / (float)(c2 > 1 ? c2 : 1);
  }
}

__global__ __launch_bounds__(256) void scatter_kernel(
    const int* __restrict__ ei, const int* __restrict__ et,
    int* __restrict__ cursor3, int* __restrict__ sorted)
{
  int e = blockIdx.x * blockDim.x + threadIdx.x;
  if (e >= NE) return;
  int s = ei[e], d = ei[NE + e], r = et[e];
  int pos = atomicAdd(&cursor3[d * 3 + r], 1);
  sorted[pos] = s;  // src only; relation implied by run
}

// ---------------- layer-0 aggregation from CSR: thread per node, run-wise ----------------
__global__ __launch_bounds__(256) void agg0_csr(
    const float* __restrict__ x, const int* __restrict__ off3, const int* __restrict__ cntR,
    const int* __restrict__ sorted, float* __restrict__ agg0)
{
  int n = blockIdx.x * blockDim.x + threadIdx.x;
  if (n >= NN) return;
  #pragma unroll
  for (int r = 0; r < 3; r++) {
    int st = off3[3 * n + r], len = cntR[3 * n + r];
    float ax = 0.f, ay = 0.f, az = 0.f;
    for (int i = 0; i < len; i++) {
      int s = sorted[st + i];
      ax += x[s * 3 + 0];
      ay += x[s * 3 + 1];
      az += x[s * 3 + 2];
    }
    agg0[n * 9 + r * 3 + 0] = ax;
    agg0[n * 9 + r * 3 + 1] = ay;
    agg0[n * 9 + r * 3 + 2] = az;
  }
}

// ---------------- pack decoder W1 (256 rows) and W2 (32x16) into B-fragment order ------------
__global__ __launch_bounds__(256) void pack_w(
    const float* __restrict__ W1, const float* __restrict__ W2,
    unsigned short* __restrict__ pk, unsigned short* __restrict__ pk2)
{
  for (int idx = threadIdx.x; idx < 8192; idx += 256) {
    int j = idx & 7, l = (idx >> 3) & 63, nt = (idx >> 9) & 1, t = idx >> 10;
    int k = t * 32 + (l >> 4) * 8 + j;
    int n = nt * 16 + (l & 15);
    pk[idx] = f2bf(W1[k * 32 + n]);
  }
  for (int idx = threadIdx.x; idx < 512; idx += 256) {
    int j = idx & 7, l = idx >> 3;
    int k = (l >> 4) * 8 + j, n = l & 15;
    pk2[idx] = f2bf(W2[k * 16 + n]);
  }
}

// ---------------- pack node-layer weights [root|W0|W1|W2] (256x64) into B-frag order ---------
__global__ __launch_bounds__(256) void pack_node_w(
    const float* __restrict__ root, const float* __restrict__ W, unsigned short* __restrict__ pkL)
{
  for (int idx = threadIdx.x; idx < 16384; idx += 256) {
    int j = idx & 7, l = (idx >> 3) & 63, nt = (idx >> 9) & 3, t = idx >> 11;
    int k = t * 32 + (l >> 4) * 8 + j;
    int n = nt * 16 + (l & 15);
    float w = (k < 64) ? root[k * 64 + n]
                       : W[((k - 64) >> 6) * 4096 + (k & 63) * 64 + n];
    pkL[idx] = f2bf(w);
  }
}

// ---- CSR aggregation: one wave/node, bf16 gather from hcat cols 0..63,
// ---- dinv-prescaled bf16 store into hcat cols 64..255 (disjoint -> race-free)
__global__ __launch_bounds__(256) void agg_csr(
    unsigned short* __restrict__ hcat, const int* __restrict__ off3, const int* __restrict__ cntR,
    const int* __restrict__ sorted, const float* __restrict__ dinv)
{
  int wid = (blockIdx.x * blockDim.x + threadIdx.x) >> 6;
  int lane = threadIdx.x & 63;
  if (wid >= NN) return;
  #pragma unroll
  for (int r = 0; r < 3; r++) {
    int st = off3[wid * 3 + r], len = cntR[wid * 3 + r];
    float a = 0.f;
    for (int base = 0; base < len; base += 64) {
      int cnt = len - base; if (cnt > 64) cnt = 64;
      int ent = (lane < cnt) ? sorted[st + base + lane] : 0;
      for (int j = 0; j < cnt; j++) {
        int s = __shfl(ent, j, 64);
        a += bf2f(hcat[(size_t)s * 256 + lane]);
      }
    }
    hcat[(size_t)wid * 256 + 64 + r * 64 + lane] = f2bf(a * dinv[wid * 3 + r]);
  }
}

// ---------------- layer 0 node update (IN=3) + relu + residual + LN ----------------
__global__ __launch_bounds__(256) void node0_kernel(
    const float* __restrict__ x, const float* __restrict__ agg0, const float* __restrict__ dinv,
    const float* __restrict__ w0, const float* __restrict__ root0, const float* __restrict__ b0,
    const float* __restrict__ res_w, const float* __restrict__ res_b,
    const float* __restrict__ g, const float* __restrict__ bb,
    float* __restrict__ h1, unsigned short* __restrict__ hcat)
{
  int wid = __builtin_amdgcn_readfirstlane((int)((blockIdx.x * blockDim.x + threadIdx.x) >> 6));
  int lane = threadIdx.x & 63;
  int n0 = wid * 8;
  if (n0 >= NN) return;
  float wr[3], ww[9], wres[3];
  #pragma unroll
  for (int i = 0; i < 3; i++) { wr[i] = root0[i * HD + lane]; wres[i] = res_w[i * HD + lane]; }
  #pragma unroll
  for (int i = 0; i < 9; i++) ww[i] = w0[i * HD + lane];
  float vb = b0[lane], vrb = res_b[lane], vg = g[lane], vbb = bb[lane];
  #pragma unroll
  for (int k = 0; k < 8; k++) {
    int nk = n0 + k;
    float xv[3];
    #pragma unroll
    for (int i = 0; i < 3; i++) xv[i] = x[nk * 3 + i];
    float v = vb;
    #pragma unroll
    for (int i = 0; i < 3; i++) v = fmaf(xv[i], wr[i], v);
    #pragma unroll
    for (int r = 0; r < 3; r++) {
      float s = 0.f;
      #pragma unroll
      for (int i = 0; i < 3; i++) s = fmaf(agg0[nk * 9 + r * 3 + i], ww[r * 3 + i], s);
      v = fmaf(dinv[nk * 3 + r], s, v);
    }
    v = fmaxf(v, 0.f);
    float res = vrb;
    #pragma unroll
    for (int i = 0; i < 3; i++) res = fmaf(xv[i], wres[i], res);
    float t = v + res;
    float mu = wave_sum(t) * 0.015625f;
    float dt = t - mu;
    float var = wave_sum(dt * dt) * 0.015625f;
    float o = dt * rsqrtf(var + 1e-5f) * vg + vbb;
    h1[nk * HD + lane] = o;
    hcat[(size_t)nk * 256 + lane] = f2bf(o);
  }
}

// ---- node update as MFMA GEMM: [h|agg*dinv] (16x256 bf16) @ [root|W0|W1|W2] (256x64) --------
// ---- + relu + fp32 residual + LN; writes fp32 hout (next residual) + bf16 into hcat cols 0..63
__global__ __launch_bounds__(256) void node_mfma(
    unsigned short* __restrict__ hcat, const float* __restrict__ hres,
    const unsigned short* __restrict__ pkL,
    const float* __restrict__ bias, const float* __restrict__ g, const float* __restrict__ bb,
    float* __restrict__ hout)
{
  int wid = (blockIdx.x * blockDim.x + threadIdx.x) >> 6;
  int lane = threadIdx.x & 63;
  int n0 = wid * 16;
  if (n0 >= NN) return;
  int m = lane & 15, gq = lane >> 4;

  const short8* Ap = (const short8*)(hcat + (size_t)(n0 + m) * 256 + gq * 8);
  const short8* Bp = (const short8*)pkL;
  f32x4 acc[4];
  #pragma unroll
  for (int nt = 0; nt < 4; nt++) acc[nt] = (f32x4){0.f, 0.f, 0.f, 0.f};
  #pragma unroll
  for (int t = 0; t < 8; t++) {
    short8 a = Ap[t * 4];  // 32 elements per K-chunk = 4 short8
    #pragma unroll
    for (int nt = 0; nt < 4; nt++)
      acc[nt] = __builtin_amdgcn_mfma_f32_16x16x32_bf16(a, Bp[(t * 4 + nt) * 64 + lane], acc[nt], 0, 0, 0);
  }

  float bias_v[4], g_v[4], bb_v[4];
  #pragma unroll
  for (int nt = 0; nt < 4; nt++) {
    bias_v[nt] = bias[nt * 16 + m];
    g_v[nt] = g[nt * 16 + m];
    bb_v[nt] = bb[nt * 16 + m];
  }
  #pragma unroll
  for (int r = 0; r < 4; r++) {
    int node = n0 + gq * 4 + r;   // C layout: row = quad*4 + reg
    float tv[4], s = 0.f;
    #pragma unroll
    for (int nt = 0; nt < 4; nt++) {
      float v = fmaxf(acc[nt][r] + bias_v[nt], 0.f) + hres[(size_t)node * HD + nt * 16 + m];
      tv[nt] = v; s += v;
    }
    #pragma unroll
    for (int o = 1; o < 16; o <<= 1) s += __shfl_xor(s, o, 64);
    float mu = s * 0.015625f;
    float s2 = 0.f;
    #pragma unroll
    for (int nt = 0; nt < 4; nt++) { float dd = tv[nt] - mu; s2 += dd * dd; }
    #pragma unroll
    for (int o = 1; o < 16; o <<= 1) s2 += __shfl_xor(s2, o, 64);
    float rstd = rsqrtf(s2 * 0.015625f + 1e-5f);
    #pragma unroll
    for (int nt = 0; nt < 4; nt++) {
      float o = (tv[nt] - mu) * rstd * g_v[nt] + bb_v[nt];
      if (hout) hout[(size_t)node * HD + nt * 16 + m] = o;
      hcat[(size_t)node * 256 + nt * 16 + m] = f2bf(o);
    }
  }
}

// ---------------- decoder: 16 edges/wave, MFMA for all three layers ----------------
__global__ __launch_bounds__(256) void decoder_mfma(
    const unsigned short* __restrict__ hcat, const int* __restrict__ ei, const float* __restrict__ ea,
    const unsigned short* __restrict__ pk, const unsigned short* __restrict__ pk2,
    const float* __restrict__ W1f, const float* __restrict__ B1,
    const float* __restrict__ B2, const float* __restrict__ W3, const float* __restrict__ B3,
    float* __restrict__ out)
{
  __shared__ float lds[4 * 32 * 19];
  int wv = threadIdx.x >> 6;
  int lane = threadIdx.x & 63;
  int e0 = (blockIdx.x * 4 + wv) * 16;
  int m = lane & 15, g = lane >> 4;

  int s = ei[e0 + m], d = ei[NE + e0 + m];
  short8 hs0 = *(const short8*)(hcat + (size_t)s * 256 + g * 8);
  short8 hs1 = *(const short8*)(hcat + (size_t)s * 256 + 32 + g * 8);
  short8 hd0 = *(const short8*)(hcat + (size_t)d * 256 + g * 8);
  short8 hd1 = *(const short8*)(hcat + (size_t)d * 256 + 32 + g * 8);

  short8 ad0, ad1, pd0, pd1;
  #pragma unroll
  for (int j = 0; j < 8; j++) {
    float a0 = bf2f((unsigned short)hs0[j]), b0 = bf2f((unsigned short)hd0[j]);
    float a1 = bf2f((unsigned short)hs1[j]), b1 = bf2f((unsigned short)hd1[j]);
    ad0[j] = (short)f2bf(fabsf(a0 - b0));
    ad1[j] = (short)f2bf(fabsf(a1 - b1));
    pd0[j] = (short)f2bf(a0 * b0);
    pd1[j] = (short)f2bf(a1 * b1);
  }

  short8 A[8] = {hs0, hs1, hd0, hd1, ad0, ad1, pd0, pd1};
  const short8* pkv = (const short8*)pk;
  f32x4 acc0 = {0.f, 0.f, 0.f, 0.f};
  f32x4 acc1 = {0.f, 0.f, 0.f, 0.f};
  #pragma unroll
  for (int t = 0; t < 8; t++) {
    acc0 = __builtin_amdgcn_mfma_f32_16x16x32_bf16(A[t], pkv[(t * 2 + 0) * 64 + lane], acc0, 0, 0, 0);
    acc1 = __builtin_amdgcn_mfma_f32_16x16x32_bf16(A[t], pkv[(t * 2 + 1) * 64 + lane], acc1, 0, 0, 0);
  }

  int cn = lane & 15;
  float wt0[6], wt1[6];
  #pragma unroll
  for (int k = 0; k < 6; k++) {
    wt0[k] = W1f[(256 + k) * 32 + cn];
    wt1[k] = W1f[(256 + k) * 32 + 16 + cn];
  }
  float b1a = B1[cn], b1b = B1[16 + cn];
  float* Z = lds + wv * 608;
  #pragma unroll
  for (int r = 0; r < 4; r++) {
    int mr = g * 4 + r;
    float z0 = acc0[r] + b1a;
    float z1 = acc1[r] + b1b;
    #pragma unroll
    for (int k = 0; k < 6; k++) {
      float eav = ea[(size_t)(e0 + mr) * 6 + k];
      z0 = fmaf(eav, wt0[k], z0);
      z1 = fmaf(eav, wt1[k], z1);
    }
    Z[cn * 19 + mr]        = fmaxf(z0, 0.f);
    Z[(16 + cn) * 19 + mr] = fmaxf(z1, 0.f);
  }

  short8 A2;
  #pragma unroll
  for (int j = 0; j < 8; j++)
    A2[j] = (short)f2bf(Z[(g * 8 + j) * 19 + m]);
  f32x4 acc2 = {0.f, 0.f, 0.f, 0.f};
  acc2 = __builtin_amdgcn_mfma_f32_16x16x32_bf16(A2, ((const short8*)pk2)[lane], acc2, 0, 0, 0);

  float bias2 = B2[m];
  float w3v = W3[m];
  float t0 = fmaxf(acc2[0] + bias2, 0.f) * w3v;
  float t1 = fmaxf(acc2[1] + bias2, 0.f) * w3v;
  float t2 = fmaxf(acc2[2] + bias2, 0.f) * w3v;
  float t3 = fmaxf(acc2[3] + bias2, 0.f) * w3v;
  #pragma unroll
  for (int off = 1; off < 16; off <<= 1) {
    t0 += __shfl_xor(t0, off, 64);
    t1 += __shfl_xor(t1, off, 64);
    t2 += __shfl_xor(t2, off, 64);
    t3 += __shfl_xor(t3, off, 64);
  }
  if (m < 4) {
    float val = (m == 0) ? t0 : (m == 1) ? t1 : (m == 2) ? t2 : t3;
    out[e0 + g * 4 + m] = val + B3[0];
  }
}

extern "C" void kernel_launch(void* const* d_in, const int* in_sizes, int n_in,
                              void* d_out, int out_size, void* d_ws, size_t ws_size,
                              hipStream_t stream) {
  const float* x      = (const float*)d_in[0];
  const int*   ei     = (const int*)d_in[1];
  const float* ea     = (const float*)d_in[2];
  const float* w0     = (const float*)d_in[3];
  const float* root0  = (const float*)d_in[4];
  const float* b0     = (const float*)d_in[5];
  const float* w1     = (const float*)d_in[6];
  const float* root1  = (const float*)d_in[7];
  const float* b1     = (const float*)d_in[8];
  const float* w2     = (const float*)d_in[9];
  const float* root2  = (const float*)d_in[10];
  const float* b2     = (const float*)d_in[11];
  const float* ln_g0  = (const float*)d_in[12];
  const float* ln_b0  = (const float*)d_in[13];
  const float* ln_g1  = (const float*)d_in[14];
  const float* ln_b1  = (const float*)d_in[15];
  const float* ln_g2  = (const float*)d_in[16];
  const float* ln_b2  = (const float*)d_in[17];
  const float* res_w  = (const float*)d_in[18];
  const float* res_b  = (const float*)d_in[19];
  const float* dec_w1 = (const float*)d_in[20];
  const float* dec_b1 = (const float*)d_in[21];
  const float* dec_w2 = (const float*)d_in[22];
  const float* dec_b2 = (const float*)d_in[23];
  const float* dec_w3 = (const float*)d_in[24];
  const float* dec_b3 = (const float*)d_in[25];

  char* ws = (char*)d_ws;
  int*   et      = (int*)(ws + 0);             //  3,200,000 B
  int*   cntR    = (int*)(ws + 3200000);       //    600,000 B  (memset 0)
  float* agg0    = (float*)(ws + 3800000);     //  1,800,000 B
  int*   bsum    = (int*)(ws + 5600000);       //      1,024 B
  int*   off3    = (int*)(ws + 5601024);       //    600,000 B
  int*   cursor3 = (int*)(ws + 6201024);       //    600,000 B
  float* dinv    = (float*)(ws + 6801024);     //    600,000 B
  int*   sorted  = (int*)(ws + 7401024);       //  3,200,000 B
  float* h1      = (float*)(ws + 10601024);    // 12,800,000 B
  float* h2      = (float*)(ws + 23401024);    // 12,800,000 B
  unsigned short* hcat = (unsigned short*)(ws + 36201024);  // 25,600,000 B
  unsigned short* pkw  = (unsigned short*)(ws + 61801024);  //     16,384 B
  unsigned short* pkw2 = (unsigned short*)(ws + 61817408);  //      1,024 B
  unsigned short* pkl1 = (unsigned short*)(ws + 61818432);  //     32,768 B
  unsigned short* pkl2 = (unsigned short*)(ws + 61851200);  //     32,768 B (end 61,883,968)

  hipMemsetAsync(cntR, 0, 600000, stream);

  edge_prep<<<(NE + 255) / 256, 256, 0, stream>>>(ei, ea, et, cntR);
  scanA<<<NB, 256, 0, stream>>>(cntR, bsum);
  scanB<<<1, 256, 0, stream>>>(bsum);
  scanC<<<NB, 256, 0, stream>>>(cntR, bsum, off3, cursor3, dinv);
  scatter_kernel<<<(NE + 255) / 256, 256, 0, stream>>>(ei, et, cursor3, sorted);
  pack_w<<<1, 256, 0, stream>>>(dec_w1, dec_w2, pkw, pkw2);
  pack_node_w<<<1, 256, 0, stream>>>(root1, w1, pkl1);
  pack_node_w<<<1, 256, 0, stream>>>(root2, w2, pkl2);
  agg0_csr<<<NB, 256, 0, stream>>>(x, off3, cntR, sorted, agg0);

  const int node0_blocks = (NN / 8 + 3) / 4;   // 8 nodes/wave, 4 waves/block
  const int agg_blocks   = (NN + 3) / 4;       // 1 node/wave, 4 waves/block
  const int mfma_blocks  = ((NN + 15) / 16 + 3) / 4;  // 16 nodes/wave

  node0_kernel<<<node0_blocks, 256, 0, stream>>>(x, agg0, dinv, w0, root0, b0,
                                                 res_w, res_b, ln_g0, ln_b0, h1, hcat);

  agg_csr<<<agg_blocks, 256, 0, stream>>>(hcat, off3, cntR, sorted, dinv);
  node_mfma<<<mfma_blocks, 256, 0, stream>>>(hcat, h1, pkl1, b1, ln_g1, ln_b1, h2);

  agg_csr<<<agg_blocks, 256, 0, stream>>>(hcat, off3, cntR, sorted, dinv);
  node_mfma<<<mfma_blocks, 256, 0, stream>>>(hcat, h2, pkl2, b2, ln_g2, ln_b2, nullptr);

  decoder_mfma<<<NE / 64, 256, 0, stream>>>(hcat, ei, ea, pkw, pkw2, dec_w1, dec_b1,
                                            dec_b2, dec_w3, dec_b3, (float*)d_out);
}